// Round 6
// baseline (471.644 us; speedup 1.0000x reference)
//
#include <hip/hip_runtime.h>
#include <math.h>

// ---------------------------------------------------------------------------
// DifferentiablePooling: 2-layer GCN + softmax + spatial loss
// Round 6: gemm1 8-wave 128x128 + A-dbuf + 1 barrier/K-step;
//          gemm2 -> pure-register MFMA f16 (no LDS, no barriers).
// ---------------------------------------------------------------------------

typedef __attribute__((ext_vector_type(8))) short bf16x8;
typedef __attribute__((ext_vector_type(4))) float f32x4;
typedef _Float16 f16;
typedef __attribute__((ext_vector_type(2))) _Float16 f16x2;
typedef __attribute__((ext_vector_type(4))) _Float16 f16x4;
typedef __attribute__((ext_vector_type(8))) _Float16 f16x8;

__device__ inline unsigned short f32_to_bf16(float f) {
    unsigned u = __float_as_uint(f);
    unsigned r = u + 0x7FFFu + ((u >> 16) & 1u);   // RTNE; inputs are finite
    return (unsigned short)(r >> 16);
}
__device__ inline float bf16_to_f32(unsigned short h) {
    return __uint_as_float((unsigned)h << 16);
}

// ---- edge dtype detection (int64 vs int32 on device) ----------------------
__global__ void detect_i64_kernel(const unsigned* __restrict__ w, int* __restrict__ flag) {
    __shared__ int red[256];
    int cnt = 0;
    for (int i = threadIdx.x; i < 4096; i += 256)
        cnt += (w[2 * i + 1] == 0u) ? 1 : 0;   // high words of int64 are 0
    red[threadIdx.x] = cnt;
    __syncthreads();
    for (int s = 128; s > 0; s >>= 1) {
        if ((int)threadIdx.x < s) red[threadIdx.x] += red[threadIdx.x + s];
        __syncthreads();
    }
    if (threadIdx.x == 0) *flag = (red[0] > 2048) ? 1 : 0;
}

// convert + fused degree count (atomicAdd on dst)
__global__ void convert_edges_kernel(const void* __restrict__ ei, int* __restrict__ es,
                                     int* __restrict__ ed, int* __restrict__ cnt,
                                     int E, const int* __restrict__ flag) {
    int idx = blockIdx.x * blockDim.x + threadIdx.x;
    if (idx >= 2 * E) return;
    int v;
    if (*flag) v = (int)((const long long*)ei)[idx];
    else       v = ((const int*)ei)[idx];
    if (idx < E) es[idx] = v;
    else { ed[idx - E] = v; atomicAdd(&cnt[v], 1); }
}

// hierarchical scan: (1) per-block inclusive scan -> row_ptr[i+1], block totals
__global__ __launch_bounds__(1024) void scan_block_kernel(const int* __restrict__ cnt,
        int* __restrict__ row_ptr, int* __restrict__ btot, int n) {
    __shared__ int buf[1024];
    int i = blockIdx.x * 1024 + threadIdx.x;
    buf[threadIdx.x] = (i < n) ? cnt[i] : 0;
    __syncthreads();
    for (int off = 1; off < 1024; off <<= 1) {
        int t = ((int)threadIdx.x >= off) ? buf[threadIdx.x - off] : 0;
        __syncthreads();
        buf[threadIdx.x] += t;
        __syncthreads();
    }
    if (i < n) row_ptr[i + 1] = buf[threadIdx.x];
    if (threadIdx.x == 1023) btot[blockIdx.x] = buf[1023];
}

// (2) inclusive scan of block totals (nb <= 1024)
__global__ __launch_bounds__(1024) void scan_tops_kernel(int* __restrict__ btot, int nb) {
    __shared__ int buf[1024];
    buf[threadIdx.x] = ((int)threadIdx.x < nb) ? btot[threadIdx.x] : 0;
    __syncthreads();
    for (int off = 1; off < 1024; off <<= 1) {
        int t = ((int)threadIdx.x >= off) ? buf[threadIdx.x - off] : 0;
        __syncthreads();
        buf[threadIdx.x] += t;
        __syncthreads();
    }
    if ((int)threadIdx.x < nb) btot[threadIdx.x] = buf[threadIdx.x];
}

// (3) add block offsets; emit cursor + dinv
__global__ void scan_finalize_kernel(int* __restrict__ row_ptr, const int* __restrict__ btot,
        const int* __restrict__ cnt, int* __restrict__ cursor, float* __restrict__ dinv, int n) {
    int i = blockIdx.x * blockDim.x + threadIdx.x;
    if (i >= n) return;
    int blk = i >> 10;
    int off = blk ? btot[blk - 1] : 0;
    int incl = row_ptr[i + 1] + off;
    row_ptr[i + 1] = incl;
    cursor[i] = incl - cnt[i];
    dinv[i] = rsqrtf((float)(cnt[i] + 1));   // +1 self loop
    if (i == 0) row_ptr[0] = 0;
}

__global__ void scatter_kernel(const int* __restrict__ es, const int* __restrict__ ed,
                               int* __restrict__ cursor, int* __restrict__ csr_src, int E) {
    int e = blockIdx.x * blockDim.x + threadIdx.x;
    if (e < E) {
        int d = ed[e];
        int p = atomicAdd(&cursor[d], 1);
        csr_src[p] = es[e];
    }
}

// ---- W1 split+transpose: W[K][N] f32 -> Wt_hi/lo[N][K] bf16 -----------------
__global__ void wsplit_kernel(const float* __restrict__ W,
                              unsigned short* __restrict__ Wt_hi,
                              unsigned short* __restrict__ Wt_lo, int K, int N) {
    int idx = blockIdx.x * 256 + threadIdx.x;
    if (idx >= K * N) return;
    int k = idx / N, n = idx % N;
    float f = W[idx];
    unsigned short h = f32_to_bf16(f);
    unsigned short l = f32_to_bf16(f - bf16_to_f32(h));
    Wt_hi[(size_t)n * K + k] = h;
    Wt_lo[(size_t)n * K + k] = l;
}

// ---- W2 split+transpose: W2[K][NC] f32 -> W2t_hi/lo[64][K] f16 (zero-padded)
__global__ void wsplit2_kernel(const float* __restrict__ W2,
                               f16* __restrict__ W2t_hi, f16* __restrict__ W2t_lo,
                               int K, int NC) {
    int idx = blockIdx.x * 256 + threadIdx.x;
    if (idx >= 64 * K) return;
    int n = idx / K, k = idx % K;
    float v = (n < NC) ? W2[(size_t)k * NC + n] : 0.f;
    f16 h = (f16)v;
    W2t_hi[idx] = h;
    W2t_lo[idx] = (f16)(v - (float)h);
}

// ---- GEMM1: h0[M,N](f16) = X[M,K] @ W1[K,N] via MFMA bf16x3 -----------------
// 128x128 tile, 8 waves (4x2), wave tile 32x64 (2x4 frags of 16x16x32).
// A staged in LDS hi/lo, DOUBLE-BUFFERED, one barrier per K-step.
// B fragments read direct from global (L2-resident Wt panel).
#define G1_BM 128
#define G1_BN 128
#define G1_BK 32
#define G1_LDK 40   // padded LDS row (bf16): 80 B rows

__global__ __launch_bounds__(512) void gemm1_mfma(
        const float* __restrict__ X, const unsigned short* __restrict__ Wt_hi,
        const unsigned short* __restrict__ Wt_lo, f16* __restrict__ C,
        int M, int K, int N) {
    __shared__ __align__(16) unsigned short Ah[2][G1_BM * G1_LDK];   // 2x10240 B
    __shared__ __align__(16) unsigned short Al[2][G1_BM * G1_LDK];   // 2x10240 B

    const int tid  = threadIdx.x;
    const int lane = tid & 63;
    const int wave = tid >> 6;        // 0..7
    const int wm   = wave & 3;        // row strip (32 rows)
    const int wn   = wave >> 2;       // col strip (64 cols)
    const int m0   = blockIdx.x * G1_BM;
    const int n0   = blockIdx.y * G1_BN;

    // A staging: 128x32 f32 = 1024 float4; 512 thr x 2
    const int arow_base = tid >> 3;   // 0..63, +64*i
    const int acq       = tid & 7;

    float4 aReg[2];

    auto load_tile = [&](int k0) {
        #pragma unroll
        for (int i = 0; i < 2; ++i) {
            int r = arow_base + 64 * i;
            int gr = m0 + r;
            if (gr < M)
                aReg[i] = ((const float4*)X)[((size_t)gr * K + k0) / 4 + acq];
            else
                aReg[i] = make_float4(0.f, 0.f, 0.f, 0.f);
        }
    };

    auto store_tile = [&](int buf) {
        #pragma unroll
        for (int i = 0; i < 2; ++i) {
            int r = arow_base + 64 * i;
            float v[4] = {aReg[i].x, aReg[i].y, aReg[i].z, aReg[i].w};
            ushort4 hi, lo;
            unsigned short* hp = (unsigned short*)&hi;
            unsigned short* lp = (unsigned short*)&lo;
            #pragma unroll
            for (int j = 0; j < 4; ++j) {
                unsigned short h = f32_to_bf16(v[j]);
                hp[j] = h;
                lp[j] = f32_to_bf16(v[j] - bf16_to_f32(h));
            }
            *(ushort4*)&Ah[buf][r * G1_LDK + acq * 4] = hi;
            *(ushort4*)&Al[buf][r * G1_LDK + acq * 4] = lo;
        }
    };

    f32x4 acc[2][4] = {};
    const int koff = (lane >> 4) * 8;
    const int frow = lane & 15;

    // per-lane B row bases (row = output column), stride K bf16
    const unsigned short* Bh_base = Wt_hi + (size_t)(n0 + wn * 64 + frow) * K + koff;
    const unsigned short* Bl_base = Wt_lo + (size_t)(n0 + wn * 64 + frow) * K + koff;

    const int nk = K / G1_BK;
    load_tile(0);
    store_tile(0);
    __syncthreads();
    for (int t = 0; t < nk; ++t) {
        const int cur = t & 1;
        const int kk = t * G1_BK;

        // B fragments for this K-step (direct from global/L2)
        bf16x8 bhf[4], blf[4];
        #pragma unroll
        for (int nn = 0; nn < 4; ++nn) {
            bhf[nn] = *(const bf16x8*)(Bh_base + (size_t)nn * 16 * K + kk);
            blf[nn] = *(const bf16x8*)(Bl_base + (size_t)nn * 16 * K + kk);
        }
        if (t + 1 < nk) load_tile((t + 1) * G1_BK);   // prefetch next A into regs

        #pragma unroll
        for (int mm = 0; mm < 2; ++mm) {
            int r = wm * 32 + mm * 16 + frow;
            bf16x8 ah = *(const bf16x8*)&Ah[cur][r * G1_LDK + koff];
            bf16x8 al = *(const bf16x8*)&Al[cur][r * G1_LDK + koff];
            #pragma unroll
            for (int nn = 0; nn < 4; ++nn)
                acc[mm][nn] = __builtin_amdgcn_mfma_f32_16x16x32_bf16(ah, bhf[nn], acc[mm][nn], 0, 0, 0);
            #pragma unroll
            for (int nn = 0; nn < 4; ++nn)
                acc[mm][nn] = __builtin_amdgcn_mfma_f32_16x16x32_bf16(ah, blf[nn], acc[mm][nn], 0, 0, 0);
            #pragma unroll
            for (int nn = 0; nn < 4; ++nn)
                acc[mm][nn] = __builtin_amdgcn_mfma_f32_16x16x32_bf16(al, bhf[nn], acc[mm][nn], 0, 0, 0);
        }
        if (t + 1 < nk) store_tile(cur ^ 1);          // write next A tile to other buffer
        __syncthreads();                               // ONE barrier per K-step
    }

    // C/D layout: col = lane&15, row = (lane>>4)*4 + i
    #pragma unroll
    for (int mm = 0; mm < 2; ++mm) {
        #pragma unroll
        for (int i = 0; i < 4; ++i) {
            int gr = m0 + wm * 32 + mm * 16 + (lane >> 4) * 4 + i;
            if (gr >= M) continue;
            #pragma unroll
            for (int nn = 0; nn < 4; ++nn) {
                int gc = n0 + wn * 64 + nn * 16 + frow;
                C[(size_t)gr * N + gc] = (f16)acc[mm][nn][i];
            }
        }
    }
}

// ---- GEMM2: g[M,NC](f16) = h[M,K](f16) @ W2[K,NC] via MFMA f16 --------------
// 64x64 tile, 4 waves (2x2), wave tile 32x32 (2x2 frags). No LDS, no barriers:
// A fragments direct from h (f16 rows), B from pre-split W2t (L2-resident).
__global__ __launch_bounds__(256) void gemm2_mfma(
        const f16* __restrict__ h, const f16* __restrict__ W2t_hi,
        const f16* __restrict__ W2t_lo, f16* __restrict__ g,
        int M, int K, int NC) {
    const int tid  = threadIdx.x;
    const int lane = tid & 63;
    const int wave = tid >> 6;       // 0..3
    const int wm   = wave & 1;       // 32-row strip
    const int wn   = wave >> 1;      // 32-col strip
    const int m0   = blockIdx.x * 64;

    const int koff = (lane >> 4) * 8;
    const int frow = lane & 15;

    f32x4 acc[2][2] = {};

    const f16* a_base[2];
    #pragma unroll
    for (int mm = 0; mm < 2; ++mm) {
        int gr = m0 + wm * 32 + mm * 16 + frow;
        a_base[mm] = h + (size_t)(gr < M ? gr : 0) * K + koff;   // clamp; rows >= M masked at store
    }
    const f16* bh_base[2];
    const f16* bl_base[2];
    #pragma unroll
    for (int nn = 0; nn < 2; ++nn) {
        int r = wn * 32 + nn * 16 + frow;     // W2t row (output col), zero-padded to 64
        bh_base[nn] = W2t_hi + (size_t)r * K + koff;
        bl_base[nn] = W2t_lo + (size_t)r * K + koff;
    }

    const int nk = K / 32;
    for (int t = 0; t < nk; ++t) {
        const int kk = t * 32;
        f16x8 a[2], bh[2], bl[2];
        #pragma unroll
        for (int mm = 0; mm < 2; ++mm) a[mm] = *(const f16x8*)(a_base[mm] + kk);
        #pragma unroll
        for (int nn = 0; nn < 2; ++nn) {
            bh[nn] = *(const f16x8*)(bh_base[nn] + kk);
            bl[nn] = *(const f16x8*)(bl_base[nn] + kk);
        }
        #pragma unroll
        for (int mm = 0; mm < 2; ++mm)
            #pragma unroll
            for (int nn = 0; nn < 2; ++nn) {
                acc[mm][nn] = __builtin_amdgcn_mfma_f32_16x16x32_f16(a[mm], bh[nn], acc[mm][nn], 0, 0, 0);
                acc[mm][nn] = __builtin_amdgcn_mfma_f32_16x16x32_f16(a[mm], bl[nn], acc[mm][nn], 0, 0, 0);
            }
    }

    #pragma unroll
    for (int mm = 0; mm < 2; ++mm) {
        #pragma unroll
        for (int i = 0; i < 4; ++i) {
            int gr = m0 + wm * 32 + mm * 16 + (lane >> 4) * 4 + i;
            if (gr >= M) continue;
            #pragma unroll
            for (int nn = 0; nn < 2; ++nn) {
                int gc = wn * 32 + nn * 16 + frow;
                if (gc < NC) g[(size_t)gr * NC + gc] = (f16)acc[mm][nn][i];
            }
        }
    }
}

// ---- layer-1 aggregation: fp16 rows, wave per dst, unroll x2 ----------------
__device__ inline float4 ld_h4(const f16x4* __restrict__ p) {
    f16x4 v = *p;
    return make_float4((float)v.x, (float)v.y, (float)v.z, (float)v.w);
}

__global__ __launch_bounds__(256) void agg1_kernel(const f16* __restrict__ h0,
        const float* __restrict__ dinv, const int* __restrict__ row_ptr,
        const int* __restrict__ csr_src, const float* __restrict__ b1,
        f16* __restrict__ h, int n) {
    int wid = (int)((blockIdx.x * (size_t)blockDim.x + threadIdx.x) >> 6);
    int lane = threadIdx.x & 63;
    if (wid >= n) return;
    const f16x4* h0v = (const f16x4*)h0;    // row = 64 f16x4
    float di = dinv[wid];
    float4 v = ld_h4(&h0v[(size_t)wid * 64 + lane]);
    float self = di * di;
    float4 acc;
    acc.x = self * v.x; acc.y = self * v.y; acc.z = self * v.z; acc.w = self * v.w;
    int beg = row_ptr[wid], end = row_ptr[wid + 1];
    int j = beg;
    for (; j + 2 <= end; j += 2) {
        int s0 = csr_src[j], s1 = csr_src[j + 1];
        float n0 = dinv[s0] * di, n1 = dinv[s1] * di;
        float4 u0 = ld_h4(&h0v[(size_t)s0 * 64 + lane]);
        float4 u1 = ld_h4(&h0v[(size_t)s1 * 64 + lane]);
        acc.x = fmaf(n0, u0.x, acc.x); acc.y = fmaf(n0, u0.y, acc.y);
        acc.z = fmaf(n0, u0.z, acc.z); acc.w = fmaf(n0, u0.w, acc.w);
        acc.x = fmaf(n1, u1.x, acc.x); acc.y = fmaf(n1, u1.y, acc.y);
        acc.z = fmaf(n1, u1.z, acc.z); acc.w = fmaf(n1, u1.w, acc.w);
    }
    if (j < end) {
        int s0 = csr_src[j];
        float n0 = dinv[s0] * di;
        float4 u0 = ld_h4(&h0v[(size_t)s0 * 64 + lane]);
        acc.x = fmaf(n0, u0.x, acc.x); acc.y = fmaf(n0, u0.y, acc.y);
        acc.z = fmaf(n0, u0.z, acc.z); acc.w = fmaf(n0, u0.w, acc.w);
    }
    float4 bb = ((const float4*)b1)[lane];
    f16x4 out;
    out.x = (f16)fmaxf(acc.x + bb.x, 0.f);
    out.y = (f16)fmaxf(acc.y + bb.y, 0.f);
    out.z = (f16)fmaxf(acc.z + bb.z, 0.f);
    out.w = (f16)fmaxf(acc.w + bb.w, 0.f);
    ((f16x4*)h)[(size_t)wid * 64 + lane] = out;
}

// ---- layer-2 aggregation + bias + row softmax (f16 g, writes S + f16 shadow)
__global__ __launch_bounds__(256) void agg2_softmax_kernel(const f16* __restrict__ g,
        const float* __restrict__ dinv, const int* __restrict__ row_ptr,
        const int* __restrict__ csr_src, const float* __restrict__ b2,
        float* __restrict__ S, f16* __restrict__ Sh, int n, int KC) {
    int wid = (int)((blockIdx.x * (size_t)blockDim.x + threadIdx.x) >> 6);
    int lane = threadIdx.x & 63;
    if (wid >= n) return;
    bool act = lane < KC;
    float di = dinv[wid];
    float acc = 0.f;
    if (act) acc = di * di * (float)g[(size_t)wid * KC + lane];
    int beg = row_ptr[wid], end = row_ptr[wid + 1];
    for (int j = beg; j < end; ++j) {
        int s = csr_src[j];
        float nrm = dinv[s] * di;
        if (act) acc = fmaf(nrm, (float)g[(size_t)s * KC + lane], acc);
    }
    float val = act ? (acc + b2[lane]) : -INFINITY;
    float m = val;
    #pragma unroll
    for (int o = 32; o > 0; o >>= 1) m = fmaxf(m, __shfl_xor(m, o));
    float e = act ? expf(val - m) : 0.f;
    float ssum = e;
    #pragma unroll
    for (int o = 32; o > 0; o >>= 1) ssum += __shfl_xor(ssum, o);
    if (act) {
        float sv = e / ssum;
        S[(size_t)wid * KC + lane] = sv;
        Sh[(size_t)wid * KC + lane] = (f16)sv;
    }
}

// ---- spatial loss on f16 S-shadow: deterministic two-stage reduction -------
__global__ __launch_bounds__(256) void loss_partial_kernel(const int* __restrict__ es,
        const int* __restrict__ ed, const float* __restrict__ pos,
        const f16* __restrict__ Sh, float* __restrict__ parts, int E, int KC) {
    float local = 0.f;
    int stride = gridDim.x * blockDim.x;
    for (int e = blockIdx.x * blockDim.x + threadIdx.x; e < E; e += stride) {
        int s = es[e], d = ed[e];
        float2 ps = ((const float2*)pos)[s];
        float2 pd = ((const float2*)pos)[d];
        float dx = ps.x - pd.x, dy = ps.y - pd.y;
        float d2 = dx * dx + dy * dy;
        const f16x2* Sa = (const f16x2*)(Sh + (size_t)s * KC);
        const f16x2* Sb = (const f16x2*)(Sh + (size_t)d * KC);
        float dot = 0.f;
        #pragma unroll
        for (int k = 0; k < 25; ++k) {
            f16x2 a = Sa[k], b = Sb[k];
            dot = fmaf((float)a.x, (float)b.x, dot);
            dot = fmaf((float)a.y, (float)b.y, dot);
        }
        local = fmaf(d2, dot, local);
    }
    __shared__ float red[256];
    red[threadIdx.x] = local;
    __syncthreads();
    for (int s = 128; s > 0; s >>= 1) {
        if ((int)threadIdx.x < s) red[threadIdx.x] += red[threadIdx.x + s];
        __syncthreads();
    }
    if (threadIdx.x == 0) parts[blockIdx.x] = red[0];
}

__global__ __launch_bounds__(1024) void loss_final_kernel(const float* __restrict__ parts,
        const float* __restrict__ sw, float* __restrict__ out, float invE) {
    __shared__ float red[1024];
    red[threadIdx.x] = parts[threadIdx.x];
    __syncthreads();
    for (int s = 512; s > 0; s >>= 1) {
        if ((int)threadIdx.x < s) red[threadIdx.x] += red[threadIdx.x + s];
        __syncthreads();
    }
    if (threadIdx.x == 0) out[0] = sw[0] * red[0] * invE;
}

// ---------------------------------------------------------------------------
extern "C" void kernel_launch(void* const* d_in, const int* in_sizes, int n_in,
                              void* d_out, int out_size, void* d_ws, size_t ws_size,
                              hipStream_t stream) {
    const float* x   = (const float*)d_in[0];
    const float* pos = (const float*)d_in[1];
    const float* W1  = (const float*)d_in[2];
    const float* b1  = (const float*)d_in[3];
    const float* W2  = (const float*)d_in[4];
    const float* b2  = (const float*)d_in[5];
    const float* sw  = (const float*)d_in[6];
    const void*  ei  = d_in[7];

    const int DH  = in_sizes[3];           // 256
    const int KC  = in_sizes[5];           // 50
    const int DIN = in_sizes[2] / DH;      // 512
    const int n   = in_sizes[0] / DIN;     // 50000
    const int E   = in_sizes[7] / 2;       // 800000

    char* p = (char*)d_ws;
    auto alloc = [&](size_t bytes) {
        char* r = p;
        p += (bytes + 255) & ~(size_t)255;
        return r;
    };
    int*   flag    = (int*)alloc(256);
    int*   es      = (int*)alloc((size_t)E * 4);
    int*   ed      = (int*)alloc((size_t)E * 4);
    int*   cnt     = (int*)alloc((size_t)n * 4);
    int*   cursor  = (int*)alloc((size_t)n * 4);
    int*   row_ptr = (int*)alloc(((size_t)n + 1) * 4);
    int*   btot    = (int*)alloc(1024 * 4);
    int*   csr     = (int*)alloc((size_t)E * 4);
    float* dinv    = (float*)alloc((size_t)n * 4);
    float* parts   = (float*)alloc(1024 * 4);
    unsigned short* Wt_hi = (unsigned short*)alloc((size_t)DIN * DH * 2);
    unsigned short* Wt_lo = (unsigned short*)alloc((size_t)DIN * DH * 2);
    f16*   W2t_hi  = (f16*)alloc((size_t)64 * DH * 2);
    f16*   W2t_lo  = (f16*)alloc((size_t)64 * DH * 2);
    f16*   h0      = (f16*)alloc((size_t)n * DH * 2);
    f16*   h       = (f16*)alloc((size_t)n * DH * 2);
    f16*   g       = (f16*)alloc((size_t)n * KC * 2);
    f16*   Sh      = (f16*)alloc((size_t)n * KC * 2);

    float* S    = (float*)d_out;
    float* Lout = S + (size_t)n * KC;

    const int nb = (n + 1023) / 1024;

    hipMemsetAsync(cnt, 0, (size_t)n * 4, stream);
    detect_i64_kernel<<<1, 256, 0, stream>>>((const unsigned*)ei, flag);
    convert_edges_kernel<<<(2 * E + 255) / 256, 256, 0, stream>>>(ei, es, ed, cnt, E, flag);
    scan_block_kernel<<<nb, 1024, 0, stream>>>(cnt, row_ptr, btot, n);
    scan_tops_kernel<<<1, 1024, 0, stream>>>(btot, nb);
    scan_finalize_kernel<<<(n + 255) / 256, 256, 0, stream>>>(row_ptr, btot, cnt, cursor, dinv, n);
    scatter_kernel<<<(E + 255) / 256, 256, 0, stream>>>(es, ed, cursor, csr, E);

    // weight prep
    wsplit_kernel<<<(DIN * DH + 255) / 256, 256, 0, stream>>>(W1, Wt_hi, Wt_lo, DIN, DH);
    wsplit2_kernel<<<(64 * DH + 255) / 256, 256, 0, stream>>>(W2, W2t_hi, W2t_lo, DH, KC);

    // h0 = x @ W1   (MFMA bf16x3, fp16 output; B direct from L2; A dbuf)
    dim3 g1((n + G1_BM - 1) / G1_BM, DH / G1_BN);
    gemm1_mfma<<<g1, 512, 0, stream>>>(x, Wt_hi, Wt_lo, h0, n, DIN, DH);

    // h = relu(Ahat @ h0 + b1)  (f16 out)
    agg1_kernel<<<(int)(((size_t)n * 64 + 255) / 256), 256, 0, stream>>>(
        h0, dinv, row_ptr, csr, b1, h, n);

    // g = h @ W2  (MFMA f16, no LDS)
    gemm2_mfma<<<(n + 63) / 64, 256, 0, stream>>>(h, W2t_hi, W2t_lo, g, n, DH, KC);

    // s = Ahat @ g + b2 ; S = softmax(s)  (+ fp16 shadow for loss)
    agg2_softmax_kernel<<<(int)(((size_t)n * 64 + 255) / 256), 256, 0, stream>>>(
        g, dinv, row_ptr, csr, b2, S, Sh, n, KC);

    // L = sw * sum(d2 * <S_s, S_d>) / E
    loss_partial_kernel<<<1024, 256, 0, stream>>>(es, ed, pos, Sh, parts, E, KC);
    loss_final_kernel<<<1, 1024, 0, stream>>>(parts, sw, Lout, 1.0f / (float)E);
}

// Round 7
// 375.780 us; speedup vs baseline: 1.2551x; 1.2551x over previous
//
#include <hip/hip_runtime.h>
#include <math.h>

// ---------------------------------------------------------------------------
// DifferentiablePooling: 2-layer GCN + softmax + spatial loss
// Round 7: gemm1 = m97-style global_load_lds staging for A(f32,swizzled) and
//          B(pre-tiled bf16 hi/lo), in-register trunc-split via v_perm,
//          32KB LDS, 4 waves, 64x64 wave tile.
// ---------------------------------------------------------------------------

typedef __attribute__((ext_vector_type(8))) short bf16x8;
typedef __attribute__((ext_vector_type(4))) float f32x4;
typedef __attribute__((ext_vector_type(4))) unsigned int u32x4;
typedef _Float16 f16;
typedef __attribute__((ext_vector_type(2))) _Float16 f16x2;
typedef __attribute__((ext_vector_type(4))) _Float16 f16x4;
typedef __attribute__((ext_vector_type(8))) _Float16 f16x8;

__device__ inline unsigned short f32_to_bf16(float f) {
    unsigned u = __float_as_uint(f);
    unsigned r = u + 0x7FFFu + ((u >> 16) & 1u);   // RTNE; inputs are finite
    return (unsigned short)(r >> 16);
}
__device__ inline float bf16_to_f32(unsigned short h) {
    return __uint_as_float((unsigned)h << 16);
}

// async global->LDS, 16B per lane; lptr must be wave-uniform (HW adds lane*16)
__device__ inline void glds16(const void* g, void* l) {
    __builtin_amdgcn_global_load_lds(
        (const __attribute__((address_space(1))) unsigned int*)g,
        (__attribute__((address_space(3))) unsigned int*)l, 16, 0, 0);
}

// ---- edge dtype detection (int64 vs int32 on device) ----------------------
__global__ void detect_i64_kernel(const unsigned* __restrict__ w, int* __restrict__ flag) {
    __shared__ int red[256];
    int cnt = 0;
    for (int i = threadIdx.x; i < 4096; i += 256)
        cnt += (w[2 * i + 1] == 0u) ? 1 : 0;   // high words of int64 are 0
    red[threadIdx.x] = cnt;
    __syncthreads();
    for (int s = 128; s > 0; s >>= 1) {
        if ((int)threadIdx.x < s) red[threadIdx.x] += red[threadIdx.x + s];
        __syncthreads();
    }
    if (threadIdx.x == 0) *flag = (red[0] > 2048) ? 1 : 0;
}

// convert + fused degree count (atomicAdd on dst)
__global__ void convert_edges_kernel(const void* __restrict__ ei, int* __restrict__ es,
                                     int* __restrict__ ed, int* __restrict__ cnt,
                                     int E, const int* __restrict__ flag) {
    int idx = blockIdx.x * blockDim.x + threadIdx.x;
    if (idx >= 2 * E) return;
    int v;
    if (*flag) v = (int)((const long long*)ei)[idx];
    else       v = ((const int*)ei)[idx];
    if (idx < E) es[idx] = v;
    else { ed[idx - E] = v; atomicAdd(&cnt[v], 1); }
}

// hierarchical scan: (1) per-block inclusive scan -> row_ptr[i+1], block totals
__global__ __launch_bounds__(1024) void scan_block_kernel(const int* __restrict__ cnt,
        int* __restrict__ row_ptr, int* __restrict__ btot, int n) {
    __shared__ int buf[1024];
    int i = blockIdx.x * 1024 + threadIdx.x;
    buf[threadIdx.x] = (i < n) ? cnt[i] : 0;
    __syncthreads();
    for (int off = 1; off < 1024; off <<= 1) {
        int t = ((int)threadIdx.x >= off) ? buf[threadIdx.x - off] : 0;
        __syncthreads();
        buf[threadIdx.x] += t;
        __syncthreads();
    }
    if (i < n) row_ptr[i + 1] = buf[threadIdx.x];
    if (threadIdx.x == 1023) btot[blockIdx.x] = buf[1023];
}

// (2) inclusive scan of block totals (nb <= 1024)
__global__ __launch_bounds__(1024) void scan_tops_kernel(int* __restrict__ btot, int nb) {
    __shared__ int buf[1024];
    buf[threadIdx.x] = ((int)threadIdx.x < nb) ? btot[threadIdx.x] : 0;
    __syncthreads();
    for (int off = 1; off < 1024; off <<= 1) {
        int t = ((int)threadIdx.x >= off) ? buf[threadIdx.x - off] : 0;
        __syncthreads();
        buf[threadIdx.x] += t;
        __syncthreads();
    }
    if ((int)threadIdx.x < nb) btot[threadIdx.x] = buf[threadIdx.x];
}

// (3) add block offsets; emit cursor + dinv
__global__ void scan_finalize_kernel(int* __restrict__ row_ptr, const int* __restrict__ btot,
        const int* __restrict__ cnt, int* __restrict__ cursor, float* __restrict__ dinv, int n) {
    int i = blockIdx.x * blockDim.x + threadIdx.x;
    if (i >= n) return;
    int blk = i >> 10;
    int off = blk ? btot[blk - 1] : 0;
    int incl = row_ptr[i + 1] + off;
    row_ptr[i + 1] = incl;
    cursor[i] = incl - cnt[i];
    dinv[i] = rsqrtf((float)(cnt[i] + 1));   // +1 self loop
    if (i == 0) row_ptr[0] = 0;
}

__global__ void scatter_kernel(const int* __restrict__ es, const int* __restrict__ ed,
                               int* __restrict__ cursor, int* __restrict__ csr_src, int E) {
    int e = blockIdx.x * blockDim.x + threadIdx.x;
    if (e < E) {
        int d = ed[e];
        int p = atomicAdd(&cursor[d], 1);
        csr_src[p] = es[e];
    }
}

// ---- W1 split + MFMA-native tiling ------------------------------------------
// W[K][N] f32 -> Th/Tl tiled bf16: elem(n,k) at ((p*nk+t)*4+kg)*1024 + np*8 + ke
// where p=n>>7, np=n&127, t=k>>5, kg=(k&31)>>3, ke=k&7.
__global__ void wsplit_kernel(const float* __restrict__ W,
                              unsigned short* __restrict__ Th,
                              unsigned short* __restrict__ Tl, int K, int N, int nk) {
    int idx = blockIdx.x * 256 + threadIdx.x;
    if (idx >= K * N) return;
    int k = idx / N, n = idx % N;
    float f = W[idx];
    unsigned short h = f32_to_bf16(f);
    unsigned short l = f32_to_bf16(f - bf16_to_f32(h));
    int p = n >> 7, np = n & 127, t = k >> 5, kg = (k & 31) >> 3, ke = k & 7;
    size_t o = ((size_t)((p * nk + t) * 4 + kg) << 10) + np * 8 + ke;
    Th[o] = h;
    Tl[o] = l;
}

// ---- W2 split+transpose: W2[K][NC] f32 -> W2t_hi/lo[64][K] f16 (zero-padded)
__global__ void wsplit2_kernel(const float* __restrict__ W2,
                               f16* __restrict__ W2t_hi, f16* __restrict__ W2t_lo,
                               int K, int NC) {
    int idx = blockIdx.x * 256 + threadIdx.x;
    if (idx >= 64 * K) return;
    int n = idx / K, k = idx % K;
    float v = (n < NC) ? W2[(size_t)k * NC + n] : 0.f;
    f16 h = (f16)v;
    W2t_hi[idx] = h;
    W2t_lo[idx] = (f16)(v - (float)h);
}

// ---- GEMM1: h0[M,N](f16) = X[M,K](f32) @ W1[K,N] via MFMA bf16x3 ------------
// 128x128 tile, 4 waves (2x2), wave 64x64 (4x4 frags of 16x16x32), BK=32.
// LDS 32KB: A f32 [128 rows][8 slots x 16B, slot^=(row&7)] = 16KB (glds,
// source pre-swizzled); Bh/Bl tiled [kg4][row128][8elem] = 8KB each (glds,
// pre-tiled global source). A hi/lo split in registers (trunc + v_perm).
#define G1_BM 128
#define G1_BN 128
#define G1_BK 32

__global__ __launch_bounds__(256) void gemm1_mfma(
        const float* __restrict__ X, const unsigned short* __restrict__ WtH,
        const unsigned short* __restrict__ WtL, f16* __restrict__ C,
        int M, int K, int N) {
    __shared__ __align__(16) unsigned char lds[32768];
    // [0,16384): A f32 swizzled; [16384,24576): Bh; [24576,32768): Bl

    const int tid  = threadIdx.x;
    const int lane = tid & 63;
    const int wave = tid >> 6;
    const int wm   = wave & 1;
    const int wn   = wave >> 1;
    const int m0   = blockIdx.x * G1_BM;
    const int pn   = blockIdx.y;          // 128-col panel index
    const int nk   = K / G1_BK;

    // --- A staging source (per-thread, swizzled slot), 4 insts of 16B -------
    const float* Xbase[4];
    #pragma unroll
    for (int i = 0; i < 4; ++i) {
        int c   = i * 256 + tid;          // LDS chunk
        int row = c >> 3;
        int sl  = (c & 7) ^ (row & 7);    // pre-swizzled source slot
        int gr  = m0 + row;
        if (gr > M - 1) gr = M - 1;       // clamp (rows >= M masked at store)
        Xbase[i] = X + (size_t)gr * K + sl * 4;
    }
    // --- B staging source (pre-tiled, fully linear) --------------------------
    const unsigned short* BhBase = WtH + ((size_t)pn * nk << 12) + (size_t)tid * 8;
    const unsigned short* BlBase = WtL + ((size_t)pn * nk << 12) + (size_t)tid * 8;

    f32x4 acc[4][4] = {};
    const int kq   = lane >> 4;           // 0..3 k-group
    const int frow = lane & 15;

    // per-lane LDS byte offsets
    const int bOff = 16384 + (kq << 11) + ((wn * 64 + frow) << 4);

    for (int t = 0; t < nk; ++t) {
        const int k0 = t * G1_BK;
        // issue staging (async), then barrier (compiler drains vmcnt)
        #pragma unroll
        for (int i = 0; i < 4; ++i)
            glds16(Xbase[i] + k0, lds + i * 4096 + wave * 1024);
        const unsigned short* bh = BhBase + (size_t)t * 4096;
        const unsigned short* bl = BlBase + (size_t)t * 4096;
        glds16(bh,        lds + 16384 + wave * 1024);
        glds16(bh + 2048, lds + 20480 + wave * 1024);
        glds16(bl,        lds + 24576 + wave * 1024);
        glds16(bl + 2048, lds + 28672 + wave * 1024);
        __syncthreads();

        // B fragments
        bf16x8 bhf[4], blf[4];
        #pragma unroll
        for (int nn = 0; nn < 4; ++nn) {
            bhf[nn] = *(const bf16x8*)(lds + bOff + nn * 256);
            blf[nn] = *(const bf16x8*)(lds + bOff + 8192 + nn * 256);
        }
        // A fragments: read f32, trunc-split to hi/lo bf16 in registers
        #pragma unroll
        for (int mm = 0; mm < 4; ++mm) {
            int ra = wm * 64 + mm * 16 + frow;
            int rb = ra << 7;
            int sw = (ra & 7) << 4;
            int s0 = kq << 1;
            f32x4 p0 = *(const f32x4*)(lds + rb + ((s0 << 4) ^ sw));
            f32x4 p1 = *(const f32x4*)(lds + rb + (((s0 + 1) << 4) ^ sw));
            float f[8] = {p0[0], p0[1], p0[2], p0[3], p1[0], p1[1], p1[2], p1[3]};
            u32x4 hv, lv;
            #pragma unroll
            for (int p = 0; p < 4; ++p) {
                unsigned b0 = __float_as_uint(f[2 * p]);
                unsigned b1 = __float_as_uint(f[2 * p + 1]);
                hv[p] = __builtin_amdgcn_perm(b1, b0, 0x07060302u);   // pack hi16s
                float l0 = f[2 * p]     - __uint_as_float(b0 & 0xFFFF0000u);
                float l1 = f[2 * p + 1] - __uint_as_float(b1 & 0xFFFF0000u);
                lv[p] = __builtin_amdgcn_perm(__float_as_uint(l1),
                                              __float_as_uint(l0), 0x07060302u);
            }
            union { u32x4 u; bf16x8 b; } ah, al;
            ah.u = hv; al.u = lv;
            #pragma unroll
            for (int nn = 0; nn < 4; ++nn)
                acc[mm][nn] = __builtin_amdgcn_mfma_f32_16x16x32_bf16(ah.b, bhf[nn], acc[mm][nn], 0, 0, 0);
            #pragma unroll
            for (int nn = 0; nn < 4; ++nn)
                acc[mm][nn] = __builtin_amdgcn_mfma_f32_16x16x32_bf16(ah.b, blf[nn], acc[mm][nn], 0, 0, 0);
            #pragma unroll
            for (int nn = 0; nn < 4; ++nn)
                acc[mm][nn] = __builtin_amdgcn_mfma_f32_16x16x32_bf16(al.b, bhf[nn], acc[mm][nn], 0, 0, 0);
        }
        __syncthreads();   // protect LDS before next iter's staging
    }

    // C/D layout: col = lane&15, row = (lane>>4)*4 + i
    const int n0 = pn * G1_BN;
    #pragma unroll
    for (int mm = 0; mm < 4; ++mm) {
        #pragma unroll
        for (int i = 0; i < 4; ++i) {
            int gr = m0 + wm * 64 + mm * 16 + kq * 4 + i;
            if (gr >= M) continue;
            #pragma unroll
            for (int nn = 0; nn < 4; ++nn) {
                int gc = n0 + wn * 64 + nn * 16 + frow;
                C[(size_t)gr * N + gc] = (f16)acc[mm][nn][i];
            }
        }
    }
}

// ---- GEMM2: g[M,NC](f16) = h[M,K](f16) @ W2[K,NC] via MFMA f16 --------------
__global__ __launch_bounds__(256) void gemm2_mfma(
        const f16* __restrict__ h, const f16* __restrict__ W2t_hi,
        const f16* __restrict__ W2t_lo, f16* __restrict__ g,
        int M, int K, int NC) {
    const int tid  = threadIdx.x;
    const int lane = tid & 63;
    const int wave = tid >> 6;
    const int wm   = wave & 1;
    const int wn   = wave >> 1;
    const int m0   = blockIdx.x * 64;

    const int koff = (lane >> 4) * 8;
    const int frow = lane & 15;

    f32x4 acc[2][2] = {};

    const f16* a_base[2];
    #pragma unroll
    for (int mm = 0; mm < 2; ++mm) {
        int gr = m0 + wm * 32 + mm * 16 + frow;
        a_base[mm] = h + (size_t)(gr < M ? gr : 0) * K + koff;
    }
    const f16* bh_base[2];
    const f16* bl_base[2];
    #pragma unroll
    for (int nn = 0; nn < 2; ++nn) {
        int r = wn * 32 + nn * 16 + frow;
        bh_base[nn] = W2t_hi + (size_t)r * K + koff;
        bl_base[nn] = W2t_lo + (size_t)r * K + koff;
    }

    const int nk = K / 32;
    for (int t = 0; t < nk; ++t) {
        const int kk = t * 32;
        f16x8 a[2], bh[2], bl[2];
        #pragma unroll
        for (int mm = 0; mm < 2; ++mm) a[mm] = *(const f16x8*)(a_base[mm] + kk);
        #pragma unroll
        for (int nn = 0; nn < 2; ++nn) {
            bh[nn] = *(const f16x8*)(bh_base[nn] + kk);
            bl[nn] = *(const f16x8*)(bl_base[nn] + kk);
        }
        #pragma unroll
        for (int mm = 0; mm < 2; ++mm)
            #pragma unroll
            for (int nn = 0; nn < 2; ++nn) {
                acc[mm][nn] = __builtin_amdgcn_mfma_f32_16x16x32_f16(a[mm], bh[nn], acc[mm][nn], 0, 0, 0);
                acc[mm][nn] = __builtin_amdgcn_mfma_f32_16x16x32_f16(a[mm], bl[nn], acc[mm][nn], 0, 0, 0);
            }
    }

    #pragma unroll
    for (int mm = 0; mm < 2; ++mm) {
        #pragma unroll
        for (int i = 0; i < 4; ++i) {
            int gr = m0 + wm * 32 + mm * 16 + (lane >> 4) * 4 + i;
            if (gr >= M) continue;
            #pragma unroll
            for (int nn = 0; nn < 2; ++nn) {
                int gc = wn * 32 + nn * 16 + frow;
                if (gc < NC) g[(size_t)gr * NC + gc] = (f16)acc[mm][nn][i];
            }
        }
    }
}

// ---- layer-1 aggregation: fp16 rows, wave per dst, unroll x2 ----------------
__device__ inline float4 ld_h4(const f16x4* __restrict__ p) {
    f16x4 v = *p;
    return make_float4((float)v.x, (float)v.y, (float)v.z, (float)v.w);
}

__global__ __launch_bounds__(256) void agg1_kernel(const f16* __restrict__ h0,
        const float* __restrict__ dinv, const int* __restrict__ row_ptr,
        const int* __restrict__ csr_src, const float* __restrict__ b1,
        f16* __restrict__ h, int n) {
    int wid = (int)((blockIdx.x * (size_t)blockDim.x + threadIdx.x) >> 6);
    int lane = threadIdx.x & 63;
    if (wid >= n) return;
    const f16x4* h0v = (const f16x4*)h0;    // row = 64 f16x4
    float di = dinv[wid];
    float4 v = ld_h4(&h0v[(size_t)wid * 64 + lane]);
    float self = di * di;
    float4 acc;
    acc.x = self * v.x; acc.y = self * v.y; acc.z = self * v.z; acc.w = self * v.w;
    int beg = row_ptr[wid], end = row_ptr[wid + 1];
    int j = beg;
    for (; j + 2 <= end; j += 2) {
        int s0 = csr_src[j], s1 = csr_src[j + 1];
        float n0 = dinv[s0] * di, n1 = dinv[s1] * di;
        float4 u0 = ld_h4(&h0v[(size_t)s0 * 64 + lane]);
        float4 u1 = ld_h4(&h0v[(size_t)s1 * 64 + lane]);
        acc.x = fmaf(n0, u0.x, acc.x); acc.y = fmaf(n0, u0.y, acc.y);
        acc.z = fmaf(n0, u0.z, acc.z); acc.w = fmaf(n0, u0.w, acc.w);
        acc.x = fmaf(n1, u1.x, acc.x); acc.y = fmaf(n1, u1.y, acc.y);
        acc.z = fmaf(n1, u1.z, acc.z); acc.w = fmaf(n1, u1.w, acc.w);
    }
    if (j < end) {
        int s0 = csr_src[j];
        float n0 = dinv[s0] * di;
        float4 u0 = ld_h4(&h0v[(size_t)s0 * 64 + lane]);
        acc.x = fmaf(n0, u0.x, acc.x); acc.y = fmaf(n0, u0.y, acc.y);
        acc.z = fmaf(n0, u0.z, acc.z); acc.w = fmaf(n0, u0.w, acc.w);
    }
    float4 bb = ((const float4*)b1)[lane];
    f16x4 out;
    out.x = (f16)fmaxf(acc.x + bb.x, 0.f);
    out.y = (f16)fmaxf(acc.y + bb.y, 0.f);
    out.z = (f16)fmaxf(acc.z + bb.z, 0.f);
    out.w = (f16)fmaxf(acc.w + bb.w, 0.f);
    ((f16x4*)h)[(size_t)wid * 64 + lane] = out;
}

// ---- layer-2 aggregation + bias + row softmax (f16 g, writes S + f16 shadow)
__global__ __launch_bounds__(256) void agg2_softmax_kernel(const f16* __restrict__ g,
        const float* __restrict__ dinv, const int* __restrict__ row_ptr,
        const int* __restrict__ csr_src, const float* __restrict__ b2,
        float* __restrict__ S, f16* __restrict__ Sh, int n, int KC) {
    int wid = (int)((blockIdx.x * (size_t)blockDim.x + threadIdx.x) >> 6);
    int lane = threadIdx.x & 63;
    if (wid >= n) return;
    bool act = lane < KC;
    float di = dinv[wid];
    float acc = 0.f;
    if (act) acc = di * di * (float)g[(size_t)wid * KC + lane];
    int beg = row_ptr[wid], end = row_ptr[wid + 1];
    for (int j = beg; j < end; ++j) {
        int s = csr_src[j];
        float nrm = dinv[s] * di;
        if (act) acc = fmaf(nrm, (float)g[(size_t)s * KC + lane], acc);
    }
    float val = act ? (acc + b2[lane]) : -INFINITY;
    float m = val;
    #pragma unroll
    for (int o = 32; o > 0; o >>= 1) m = fmaxf(m, __shfl_xor(m, o));
    float e = act ? expf(val - m) : 0.f;
    float ssum = e;
    #pragma unroll
    for (int o = 32; o > 0; o >>= 1) ssum += __shfl_xor(ssum, o);
    if (act) {
        float sv = e / ssum;
        S[(size_t)wid * KC + lane] = sv;
        Sh[(size_t)wid * KC + lane] = (f16)sv;
    }
}

// ---- spatial loss on f16 S-shadow: deterministic two-stage reduction -------
__global__ __launch_bounds__(256) void loss_partial_kernel(const int* __restrict__ es,
        const int* __restrict__ ed, const float* __restrict__ pos,
        const f16* __restrict__ Sh, float* __restrict__ parts, int E, int KC) {
    float local = 0.f;
    int stride = gridDim.x * blockDim.x;
    for (int e = blockIdx.x * blockDim.x + threadIdx.x; e < E; e += stride) {
        int s = es[e], d = ed[e];
        float2 ps = ((const float2*)pos)[s];
        float2 pd = ((const float2*)pos)[d];
        float dx = ps.x - pd.x, dy = ps.y - pd.y;
        float d2 = dx * dx + dy * dy;
        const f16x2* Sa = (const f16x2*)(Sh + (size_t)s * KC);
        const f16x2* Sb = (const f16x2*)(Sh + (size_t)d * KC);
        float dot = 0.f;
        #pragma unroll
        for (int k = 0; k < 25; ++k) {
            f16x2 a = Sa[k], b = Sb[k];
            dot = fmaf((float)a.x, (float)b.x, dot);
            dot = fmaf((float)a.y, (float)b.y, dot);
        }
        local = fmaf(d2, dot, local);
    }
    __shared__ float red[256];
    red[threadIdx.x] = local;
    __syncthreads();
    for (int s = 128; s > 0; s >>= 1) {
        if ((int)threadIdx.x < s) red[threadIdx.x] += red[threadIdx.x + s];
        __syncthreads();
    }
    if (threadIdx.x == 0) parts[blockIdx.x] = red[0];
}

__global__ __launch_bounds__(1024) void loss_final_kernel(const float* __restrict__ parts,
        const float* __restrict__ sw, float* __restrict__ out, float invE) {
    __shared__ float red[1024];
    red[threadIdx.x] = parts[threadIdx.x];
    __syncthreads();
    for (int s = 512; s > 0; s >>= 1) {
        if ((int)threadIdx.x < s) red[threadIdx.x] += red[threadIdx.x + s];
        __syncthreads();
    }
    if (threadIdx.x == 0) out[0] = sw[0] * red[0] * invE;
}

// ---------------------------------------------------------------------------
extern "C" void kernel_launch(void* const* d_in, const int* in_sizes, int n_in,
                              void* d_out, int out_size, void* d_ws, size_t ws_size,
                              hipStream_t stream) {
    const float* x   = (const float*)d_in[0];
    const float* pos = (const float*)d_in[1];
    const float* W1  = (const float*)d_in[2];
    const float* b1  = (const float*)d_in[3];
    const float* W2  = (const float*)d_in[4];
    const float* b2  = (const float*)d_in[5];
    const float* sw  = (const float*)d_in[6];
    const void*  ei  = d_in[7];

    const int DH  = in_sizes[3];           // 256
    const int KC  = in_sizes[5];           // 50
    const int DIN = in_sizes[2] / DH;      // 512
    const int n   = in_sizes[0] / DIN;     // 50000
    const int E   = in_sizes[7] / 2;       // 800000

    char* p = (char*)d_ws;
    auto alloc = [&](size_t bytes) {
        char* r = p;
        p += (bytes + 255) & ~(size_t)255;
        return r;
    };
    int*   flag    = (int*)alloc(256);
    int*   es      = (int*)alloc((size_t)E * 4);
    int*   ed      = (int*)alloc((size_t)E * 4);
    int*   cnt     = (int*)alloc((size_t)n * 4);
    int*   cursor  = (int*)alloc((size_t)n * 4);
    int*   row_ptr = (int*)alloc(((size_t)n + 1) * 4);
    int*   btot    = (int*)alloc(1024 * 4);
    int*   csr     = (int*)alloc((size_t)E * 4);
    float* dinv    = (float*)alloc((size_t)n * 4);
    float* parts   = (float*)alloc(1024 * 4);
    unsigned short* Wt_hi = (unsigned short*)alloc((size_t)DIN * DH * 2);
    unsigned short* Wt_lo = (unsigned short*)alloc((size_t)DIN * DH * 2);
    f16*   W2t_hi  = (f16*)alloc((size_t)64 * DH * 2);
    f16*   W2t_lo  = (f16*)alloc((size_t)64 * DH * 2);
    f16*   h0      = (f16*)alloc((size_t)n * DH * 2);
    f16*   h       = (f16*)alloc((size_t)n * DH * 2);
    f16*   g       = (f16*)alloc((size_t)n * KC * 2);
    f16*   Sh      = (f16*)alloc((size_t)n * KC * 2);

    float* S    = (float*)d_out;
    float* Lout = S + (size_t)n * KC;

    const int nb = (n + 1023) / 1024;
    const int nk = DIN / G1_BK;

    hipMemsetAsync(cnt, 0, (size_t)n * 4, stream);
    detect_i64_kernel<<<1, 256, 0, stream>>>((const unsigned*)ei, flag);
    convert_edges_kernel<<<(2 * E + 255) / 256, 256, 0, stream>>>(ei, es, ed, cnt, E, flag);
    scan_block_kernel<<<nb, 1024, 0, stream>>>(cnt, row_ptr, btot, n);
    scan_tops_kernel<<<1, 1024, 0, stream>>>(btot, nb);
    scan_finalize_kernel<<<(n + 255) / 256, 256, 0, stream>>>(row_ptr, btot, cnt, cursor, dinv, n);
    scatter_kernel<<<(E + 255) / 256, 256, 0, stream>>>(es, ed, cursor, csr, E);

    // weight prep
    wsplit_kernel<<<(DIN * DH + 255) / 256, 256, 0, stream>>>(W1, Wt_hi, Wt_lo, DIN, DH, nk);
    wsplit2_kernel<<<(64 * DH + 255) / 256, 256, 0, stream>>>(W2, W2t_hi, W2t_lo, DH, KC);

    // h0 = x @ W1   (MFMA bf16x3; glds staging; fp16 output)
    dim3 g1((n + G1_BM - 1) / G1_BM, DH / G1_BN);
    gemm1_mfma<<<g1, 256, 0, stream>>>(x, Wt_hi, Wt_lo, h0, n, DIN, DH);

    // h = relu(Ahat @ h0 + b1)  (f16 out)
    agg1_kernel<<<(int)(((size_t)n * 64 + 255) / 256), 256, 0, stream>>>(
        h0, dinv, row_ptr, csr, b1, h, n);

    // g = h @ W2  (MFMA f16, no LDS)
    gemm2_mfma<<<(n + 63) / 64, 256, 0, stream>>>(h, W2t_hi, W2t_lo, g, n, DH, KC);

    // s = Ahat @ g + b2 ; S = softmax(s)  (+ fp16 shadow for loss)
    agg2_softmax_kernel<<<(int)(((size_t)n * 64 + 255) / 256), 256, 0, stream>>>(
        g, dinv, row_ptr, csr, b2, S, Sh, n, KC);

    // L = sw * sum(d2 * <S_s, S_d>) / E
    loss_partial_kernel<<<1024, 256, 0, stream>>>(es, ed, pos, Sh, parts, E, KC);
    loss_final_kernel<<<1, 1024, 0, stream>>>(parts, sw, Lout, 1.0f / (float)E);
}

// Round 8
// 348.637 us; speedup vs baseline: 1.3528x; 1.0779x over previous
//
#include <hip/hip_runtime.h>
#include <math.h>

// ---------------------------------------------------------------------------
// DifferentiablePooling: 2-layer GCN + softmax + spatial loss
// Round 8: csr_nrm precompute (kills dependent dinv gather), agg2 4-way
//          edge unroll with independent accumulators.
// ---------------------------------------------------------------------------

typedef __attribute__((ext_vector_type(8))) short bf16x8;
typedef __attribute__((ext_vector_type(4))) float f32x4;
typedef __attribute__((ext_vector_type(4))) unsigned int u32x4;
typedef _Float16 f16;
typedef __attribute__((ext_vector_type(2))) _Float16 f16x2;
typedef __attribute__((ext_vector_type(4))) _Float16 f16x4;
typedef __attribute__((ext_vector_type(8))) _Float16 f16x8;

__device__ inline unsigned short f32_to_bf16(float f) {
    unsigned u = __float_as_uint(f);
    unsigned r = u + 0x7FFFu + ((u >> 16) & 1u);   // RTNE; inputs are finite
    return (unsigned short)(r >> 16);
}
__device__ inline float bf16_to_f32(unsigned short h) {
    return __uint_as_float((unsigned)h << 16);
}

// async global->LDS, 16B per lane; lptr must be wave-uniform (HW adds lane*16)
__device__ inline void glds16(const void* g, void* l) {
    __builtin_amdgcn_global_load_lds(
        (const __attribute__((address_space(1))) unsigned int*)g,
        (__attribute__((address_space(3))) unsigned int*)l, 16, 0, 0);
}

// ---- edge dtype detection (int64 vs int32 on device) ----------------------
__global__ void detect_i64_kernel(const unsigned* __restrict__ w, int* __restrict__ flag) {
    __shared__ int red[256];
    int cnt = 0;
    for (int i = threadIdx.x; i < 4096; i += 256)
        cnt += (w[2 * i + 1] == 0u) ? 1 : 0;   // high words of int64 are 0
    red[threadIdx.x] = cnt;
    __syncthreads();
    for (int s = 128; s > 0; s >>= 1) {
        if ((int)threadIdx.x < s) red[threadIdx.x] += red[threadIdx.x + s];
        __syncthreads();
    }
    if (threadIdx.x == 0) *flag = (red[0] > 2048) ? 1 : 0;
}

// convert + fused degree count (atomicAdd on dst)
__global__ void convert_edges_kernel(const void* __restrict__ ei, int* __restrict__ es,
                                     int* __restrict__ ed, int* __restrict__ cnt,
                                     int E, const int* __restrict__ flag) {
    int idx = blockIdx.x * blockDim.x + threadIdx.x;
    if (idx >= 2 * E) return;
    int v;
    if (*flag) v = (int)((const long long*)ei)[idx];
    else       v = ((const int*)ei)[idx];
    if (idx < E) es[idx] = v;
    else { ed[idx - E] = v; atomicAdd(&cnt[v], 1); }
}

// hierarchical scan: (1) per-block inclusive scan -> row_ptr[i+1], block totals
__global__ __launch_bounds__(1024) void scan_block_kernel(const int* __restrict__ cnt,
        int* __restrict__ row_ptr, int* __restrict__ btot, int n) {
    __shared__ int buf[1024];
    int i = blockIdx.x * 1024 + threadIdx.x;
    buf[threadIdx.x] = (i < n) ? cnt[i] : 0;
    __syncthreads();
    for (int off = 1; off < 1024; off <<= 1) {
        int t = ((int)threadIdx.x >= off) ? buf[threadIdx.x - off] : 0;
        __syncthreads();
        buf[threadIdx.x] += t;
        __syncthreads();
    }
    if (i < n) row_ptr[i + 1] = buf[threadIdx.x];
    if (threadIdx.x == 1023) btot[blockIdx.x] = buf[1023];
}

// (2) inclusive scan of block totals (nb <= 1024)
__global__ __launch_bounds__(1024) void scan_tops_kernel(int* __restrict__ btot, int nb) {
    __shared__ int buf[1024];
    buf[threadIdx.x] = ((int)threadIdx.x < nb) ? btot[threadIdx.x] : 0;
    __syncthreads();
    for (int off = 1; off < 1024; off <<= 1) {
        int t = ((int)threadIdx.x >= off) ? buf[threadIdx.x - off] : 0;
        __syncthreads();
        buf[threadIdx.x] += t;
        __syncthreads();
    }
    if ((int)threadIdx.x < nb) btot[threadIdx.x] = buf[threadIdx.x];
}

// (3) add block offsets; emit cursor + dinv
__global__ void scan_finalize_kernel(int* __restrict__ row_ptr, const int* __restrict__ btot,
        const int* __restrict__ cnt, int* __restrict__ cursor, float* __restrict__ dinv, int n) {
    int i = blockIdx.x * blockDim.x + threadIdx.x;
    if (i >= n) return;
    int blk = i >> 10;
    int off = blk ? btot[blk - 1] : 0;
    int incl = row_ptr[i + 1] + off;
    row_ptr[i + 1] = incl;
    cursor[i] = incl - cnt[i];
    dinv[i] = rsqrtf((float)(cnt[i] + 1));   // +1 self loop
    if (i == 0) row_ptr[0] = 0;
}

// scatter + per-entry source norm (dinv[src]) for dependent-load-free agg
__global__ void scatter_kernel(const int* __restrict__ es, const int* __restrict__ ed,
                               const float* __restrict__ dinv, int* __restrict__ cursor,
                               int* __restrict__ csr_src, float* __restrict__ csr_nrm, int E) {
    int e = blockIdx.x * blockDim.x + threadIdx.x;
    if (e < E) {
        int s = es[e];
        int d = ed[e];
        int p = atomicAdd(&cursor[d], 1);
        csr_src[p] = s;
        csr_nrm[p] = dinv[s];
    }
}

// ---- W1 split + MFMA-native tiling ------------------------------------------
__global__ void wsplit_kernel(const float* __restrict__ W,
                              unsigned short* __restrict__ Th,
                              unsigned short* __restrict__ Tl, int K, int N, int nk) {
    int idx = blockIdx.x * 256 + threadIdx.x;
    if (idx >= K * N) return;
    int k = idx / N, n = idx % N;
    float f = W[idx];
    unsigned short h = f32_to_bf16(f);
    unsigned short l = f32_to_bf16(f - bf16_to_f32(h));
    int p = n >> 7, np = n & 127, t = k >> 5, kg = (k & 31) >> 3, ke = k & 7;
    size_t o = ((size_t)((p * nk + t) * 4 + kg) << 10) + np * 8 + ke;
    Th[o] = h;
    Tl[o] = l;
}

// ---- W2 split+transpose: W2[K][NC] f32 -> W2t_hi/lo[64][K] f16 (zero-padded)
__global__ void wsplit2_kernel(const float* __restrict__ W2,
                               f16* __restrict__ W2t_hi, f16* __restrict__ W2t_lo,
                               int K, int NC) {
    int idx = blockIdx.x * 256 + threadIdx.x;
    if (idx >= 64 * K) return;
    int n = idx / K, k = idx % K;
    float v = (n < NC) ? W2[(size_t)k * NC + n] : 0.f;
    f16 h = (f16)v;
    W2t_hi[idx] = h;
    W2t_lo[idx] = (f16)(v - (float)h);
}

// ---- GEMM1: h0[M,N](f16) = X[M,K](f32) @ W1[K,N] via MFMA bf16x3 ------------
#define G1_BM 128
#define G1_BN 128
#define G1_BK 32

__global__ __launch_bounds__(256) void gemm1_mfma(
        const float* __restrict__ X, const unsigned short* __restrict__ WtH,
        const unsigned short* __restrict__ WtL, f16* __restrict__ C,
        int M, int K, int N) {
    __shared__ __align__(16) unsigned char lds[32768];
    // [0,16384): A f32 swizzled; [16384,24576): Bh; [24576,32768): Bl

    const int tid  = threadIdx.x;
    const int lane = tid & 63;
    const int wave = tid >> 6;
    const int wm   = wave & 1;
    const int wn   = wave >> 1;
    const int m0   = blockIdx.x * G1_BM;
    const int pn   = blockIdx.y;          // 128-col panel index
    const int nk   = K / G1_BK;

    const float* Xbase[4];
    #pragma unroll
    for (int i = 0; i < 4; ++i) {
        int c   = i * 256 + tid;
        int row = c >> 3;
        int sl  = (c & 7) ^ (row & 7);    // pre-swizzled source slot
        int gr  = m0 + row;
        if (gr > M - 1) gr = M - 1;
        Xbase[i] = X + (size_t)gr * K + sl * 4;
    }
    const unsigned short* BhBase = WtH + ((size_t)pn * nk << 12) + (size_t)tid * 8;
    const unsigned short* BlBase = WtL + ((size_t)pn * nk << 12) + (size_t)tid * 8;

    f32x4 acc[4][4] = {};
    const int kq   = lane >> 4;
    const int frow = lane & 15;
    const int bOff = 16384 + (kq << 11) + ((wn * 64 + frow) << 4);

    for (int t = 0; t < nk; ++t) {
        const int k0 = t * G1_BK;
        #pragma unroll
        for (int i = 0; i < 4; ++i)
            glds16(Xbase[i] + k0, lds + i * 4096 + wave * 1024);
        const unsigned short* bh = BhBase + (size_t)t * 4096;
        const unsigned short* bl = BlBase + (size_t)t * 4096;
        glds16(bh,        lds + 16384 + wave * 1024);
        glds16(bh + 2048, lds + 20480 + wave * 1024);
        glds16(bl,        lds + 24576 + wave * 1024);
        glds16(bl + 2048, lds + 28672 + wave * 1024);
        __syncthreads();

        bf16x8 bhf[4], blf[4];
        #pragma unroll
        for (int nn = 0; nn < 4; ++nn) {
            bhf[nn] = *(const bf16x8*)(lds + bOff + nn * 256);
            blf[nn] = *(const bf16x8*)(lds + bOff + 8192 + nn * 256);
        }
        #pragma unroll
        for (int mm = 0; mm < 4; ++mm) {
            int ra = wm * 64 + mm * 16 + frow;
            int rb = ra << 7;
            int sw = (ra & 7) << 4;
            int s0 = kq << 1;
            f32x4 p0 = *(const f32x4*)(lds + rb + ((s0 << 4) ^ sw));
            f32x4 p1 = *(const f32x4*)(lds + rb + (((s0 + 1) << 4) ^ sw));
            float f[8] = {p0[0], p0[1], p0[2], p0[3], p1[0], p1[1], p1[2], p1[3]};
            u32x4 hv, lv;
            #pragma unroll
            for (int p = 0; p < 4; ++p) {
                unsigned b0 = __float_as_uint(f[2 * p]);
                unsigned b1 = __float_as_uint(f[2 * p + 1]);
                hv[p] = __builtin_amdgcn_perm(b1, b0, 0x07060302u);
                float l0 = f[2 * p]     - __uint_as_float(b0 & 0xFFFF0000u);
                float l1 = f[2 * p + 1] - __uint_as_float(b1 & 0xFFFF0000u);
                lv[p] = __builtin_amdgcn_perm(__float_as_uint(l1),
                                              __float_as_uint(l0), 0x07060302u);
            }
            union { u32x4 u; bf16x8 b; } ah, al;
            ah.u = hv; al.u = lv;
            #pragma unroll
            for (int nn = 0; nn < 4; ++nn)
                acc[mm][nn] = __builtin_amdgcn_mfma_f32_16x16x32_bf16(ah.b, bhf[nn], acc[mm][nn], 0, 0, 0);
            #pragma unroll
            for (int nn = 0; nn < 4; ++nn)
                acc[mm][nn] = __builtin_amdgcn_mfma_f32_16x16x32_bf16(ah.b, blf[nn], acc[mm][nn], 0, 0, 0);
            #pragma unroll
            for (int nn = 0; nn < 4; ++nn)
                acc[mm][nn] = __builtin_amdgcn_mfma_f32_16x16x32_bf16(al.b, bhf[nn], acc[mm][nn], 0, 0, 0);
        }
        __syncthreads();
    }

    const int n0 = pn * G1_BN;
    #pragma unroll
    for (int mm = 0; mm < 4; ++mm) {
        #pragma unroll
        for (int i = 0; i < 4; ++i) {
            int gr = m0 + wm * 64 + mm * 16 + kq * 4 + i;
            if (gr >= M) continue;
            #pragma unroll
            for (int nn = 0; nn < 4; ++nn) {
                int gc = n0 + wn * 64 + nn * 16 + frow;
                C[(size_t)gr * N + gc] = (f16)acc[mm][nn][i];
            }
        }
    }
}

// ---- GEMM2: g[M,NC](f16) = h[M,K](f16) @ W2[K,NC] via MFMA f16 --------------
__global__ __launch_bounds__(256) void gemm2_mfma(
        const f16* __restrict__ h, const f16* __restrict__ W2t_hi,
        const f16* __restrict__ W2t_lo, f16* __restrict__ g,
        int M, int K, int NC) {
    const int tid  = threadIdx.x;
    const int lane = tid & 63;
    const int wave = tid >> 6;
    const int wm   = wave & 1;
    const int wn   = wave >> 1;
    const int m0   = blockIdx.x * 64;

    const int koff = (lane >> 4) * 8;
    const int frow = lane & 15;

    f32x4 acc[2][2] = {};

    const f16* a_base[2];
    #pragma unroll
    for (int mm = 0; mm < 2; ++mm) {
        int gr = m0 + wm * 32 + mm * 16 + frow;
        a_base[mm] = h + (size_t)(gr < M ? gr : 0) * K + koff;
    }
    const f16* bh_base[2];
    const f16* bl_base[2];
    #pragma unroll
    for (int nn = 0; nn < 2; ++nn) {
        int r = wn * 32 + nn * 16 + frow;
        bh_base[nn] = W2t_hi + (size_t)r * K + koff;
        bl_base[nn] = W2t_lo + (size_t)r * K + koff;
    }

    const int nk = K / 32;
    for (int t = 0; t < nk; ++t) {
        const int kk = t * 32;
        f16x8 a[2], bh[2], bl[2];
        #pragma unroll
        for (int mm = 0; mm < 2; ++mm) a[mm] = *(const f16x8*)(a_base[mm] + kk);
        #pragma unroll
        for (int nn = 0; nn < 2; ++nn) {
            bh[nn] = *(const f16x8*)(bh_base[nn] + kk);
            bl[nn] = *(const f16x8*)(bl_base[nn] + kk);
        }
        #pragma unroll
        for (int mm = 0; mm < 2; ++mm)
            #pragma unroll
            for (int nn = 0; nn < 2; ++nn) {
                acc[mm][nn] = __builtin_amdgcn_mfma_f32_16x16x32_f16(a[mm], bh[nn], acc[mm][nn], 0, 0, 0);
                acc[mm][nn] = __builtin_amdgcn_mfma_f32_16x16x32_f16(a[mm], bl[nn], acc[mm][nn], 0, 0, 0);
            }
    }

    #pragma unroll
    for (int mm = 0; mm < 2; ++mm) {
        #pragma unroll
        for (int i = 0; i < 4; ++i) {
            int gr = m0 + wm * 32 + mm * 16 + (lane >> 4) * 4 + i;
            if (gr >= M) continue;
            #pragma unroll
            for (int nn = 0; nn < 2; ++nn) {
                int gc = wn * 32 + nn * 16 + frow;
                if (gc < NC) g[(size_t)gr * NC + gc] = (f16)acc[mm][nn][i];
            }
        }
    }
}

// ---- layer-1 aggregation: fp16 rows, wave per dst, unroll x2, csr_nrm -------
__device__ inline float4 ld_h4(const f16x4* __restrict__ p) {
    f16x4 v = *p;
    return make_float4((float)v.x, (float)v.y, (float)v.z, (float)v.w);
}

__global__ __launch_bounds__(256) void agg1_kernel(const f16* __restrict__ h0,
        const float* __restrict__ dinv, const int* __restrict__ row_ptr,
        const int* __restrict__ csr_src, const float* __restrict__ csr_nrm,
        const float* __restrict__ b1, f16* __restrict__ h, int n) {
    int wid = (int)((blockIdx.x * (size_t)blockDim.x + threadIdx.x) >> 6);
    int lane = threadIdx.x & 63;
    if (wid >= n) return;
    const f16x4* h0v = (const f16x4*)h0;    // row = 64 f16x4
    float di = dinv[wid];
    float4 v = ld_h4(&h0v[(size_t)wid * 64 + lane]);
    float self = di * di;
    float4 acc;
    acc.x = self * v.x; acc.y = self * v.y; acc.z = self * v.z; acc.w = self * v.w;
    int beg = row_ptr[wid], end = row_ptr[wid + 1];
    int j = beg;
    for (; j + 2 <= end; j += 2) {
        int s0 = csr_src[j], s1 = csr_src[j + 1];
        float n0 = csr_nrm[j] * di, n1 = csr_nrm[j + 1] * di;
        float4 u0 = ld_h4(&h0v[(size_t)s0 * 64 + lane]);
        float4 u1 = ld_h4(&h0v[(size_t)s1 * 64 + lane]);
        acc.x = fmaf(n0, u0.x, acc.x); acc.y = fmaf(n0, u0.y, acc.y);
        acc.z = fmaf(n0, u0.z, acc.z); acc.w = fmaf(n0, u0.w, acc.w);
        acc.x = fmaf(n1, u1.x, acc.x); acc.y = fmaf(n1, u1.y, acc.y);
        acc.z = fmaf(n1, u1.z, acc.z); acc.w = fmaf(n1, u1.w, acc.w);
    }
    if (j < end) {
        int s0 = csr_src[j];
        float n0 = csr_nrm[j] * di;
        float4 u0 = ld_h4(&h0v[(size_t)s0 * 64 + lane]);
        acc.x = fmaf(n0, u0.x, acc.x); acc.y = fmaf(n0, u0.y, acc.y);
        acc.z = fmaf(n0, u0.z, acc.z); acc.w = fmaf(n0, u0.w, acc.w);
    }
    float4 bb = ((const float4*)b1)[lane];
    f16x4 out;
    out.x = (f16)fmaxf(acc.x + bb.x, 0.f);
    out.y = (f16)fmaxf(acc.y + bb.y, 0.f);
    out.z = (f16)fmaxf(acc.z + bb.z, 0.f);
    out.w = (f16)fmaxf(acc.w + bb.w, 0.f);
    ((f16x4*)h)[(size_t)wid * 64 + lane] = out;
}

// ---- layer-2 aggregation + softmax: 4-way unroll, csr_nrm -------------------
__global__ __launch_bounds__(256) void agg2_softmax_kernel(const f16* __restrict__ g,
        const float* __restrict__ dinv, const int* __restrict__ row_ptr,
        const int* __restrict__ csr_src, const float* __restrict__ csr_nrm,
        const float* __restrict__ b2, float* __restrict__ S, f16* __restrict__ Sh,
        int n, int KC) {
    int wid = (int)((blockIdx.x * (size_t)blockDim.x + threadIdx.x) >> 6);
    int lane = threadIdx.x & 63;
    if (wid >= n) return;
    bool act = lane < KC;
    size_t gidx = act ? (size_t)lane : 0;
    float di = dinv[wid];
    float a0 = 0.f, a1 = 0.f, a2 = 0.f, a3 = 0.f;
    if (act) a0 = di * di * (float)g[(size_t)wid * KC + lane];
    int beg = row_ptr[wid], end = row_ptr[wid + 1];
    int j = beg;
    for (; j + 4 <= end; j += 4) {
        int s0 = csr_src[j], s1 = csr_src[j + 1], s2 = csr_src[j + 2], s3 = csr_src[j + 3];
        float4 nv = *(const float4*)(csr_nrm + j);     // 16B-aligned? j arbitrary -> use per-elem
        float n0 = csr_nrm[j]     * di;
        float n1 = csr_nrm[j + 1] * di;
        float n2 = csr_nrm[j + 2] * di;
        float n3 = csr_nrm[j + 3] * di;
        (void)nv;
        float g0 = (float)g[(size_t)s0 * KC + gidx];
        float g1 = (float)g[(size_t)s1 * KC + gidx];
        float g2 = (float)g[(size_t)s2 * KC + gidx];
        float g3 = (float)g[(size_t)s3 * KC + gidx];
        a0 = fmaf(n0, g0, a0);
        a1 = fmaf(n1, g1, a1);
        a2 = fmaf(n2, g2, a2);
        a3 = fmaf(n3, g3, a3);
    }
    for (; j < end; ++j) {
        int s0 = csr_src[j];
        float n0 = csr_nrm[j] * di;
        a0 = fmaf(n0, (float)g[(size_t)s0 * KC + gidx], a0);
    }
    float acc = (a0 + a1) + (a2 + a3);
    float val = act ? (acc + b2[lane]) : -INFINITY;
    float m = val;
    #pragma unroll
    for (int o = 32; o > 0; o >>= 1) m = fmaxf(m, __shfl_xor(m, o));
    float e = act ? expf(val - m) : 0.f;
    float ssum = e;
    #pragma unroll
    for (int o = 32; o > 0; o >>= 1) ssum += __shfl_xor(ssum, o);
    if (act) {
        float sv = e / ssum;
        S[(size_t)wid * KC + lane] = sv;
        Sh[(size_t)wid * KC + lane] = (f16)sv;
    }
}

// ---- spatial loss on f16 S-shadow: deterministic two-stage reduction -------
__global__ __launch_bounds__(256) void loss_partial_kernel(const int* __restrict__ es,
        const int* __restrict__ ed, const float* __restrict__ pos,
        const f16* __restrict__ Sh, float* __restrict__ parts, int E, int KC) {
    float local = 0.f;
    int stride = gridDim.x * blockDim.x;
    for (int e = blockIdx.x * blockDim.x + threadIdx.x; e < E; e += stride) {
        int s = es[e], d = ed[e];
        float2 ps = ((const float2*)pos)[s];
        float2 pd = ((const float2*)pos)[d];
        float dx = ps.x - pd.x, dy = ps.y - pd.y;
        float d2 = dx * dx + dy * dy;
        const f16x2* Sa = (const f16x2*)(Sh + (size_t)s * KC);
        const f16x2* Sb = (const f16x2*)(Sh + (size_t)d * KC);
        float dot = 0.f;
        #pragma unroll
        for (int k = 0; k < 25; ++k) {
            f16x2 a = Sa[k], b = Sb[k];
            dot = fmaf((float)a.x, (float)b.x, dot);
            dot = fmaf((float)a.y, (float)b.y, dot);
        }
        local = fmaf(d2, dot, local);
    }
    __shared__ float red[256];
    red[threadIdx.x] = local;
    __syncthreads();
    for (int s = 128; s > 0; s >>= 1) {
        if ((int)threadIdx.x < s) red[threadIdx.x] += red[threadIdx.x + s];
        __syncthreads();
    }
    if (threadIdx.x == 0) parts[blockIdx.x] = red[0];
}

__global__ __launch_bounds__(1024) void loss_final_kernel(const float* __restrict__ parts,
        const float* __restrict__ sw, float* __restrict__ out, float invE) {
    __shared__ float red[1024];
    red[threadIdx.x] = parts[threadIdx.x];
    __syncthreads();
    for (int s = 512; s > 0; s >>= 1) {
        if ((int)threadIdx.x < s) red[threadIdx.x] += red[threadIdx.x + s];
        __syncthreads();
    }
    if (threadIdx.x == 0) out[0] = sw[0] * red[0] * invE;
}

// ---------------------------------------------------------------------------
extern "C" void kernel_launch(void* const* d_in, const int* in_sizes, int n_in,
                              void* d_out, int out_size, void* d_ws, size_t ws_size,
                              hipStream_t stream) {
    const float* x   = (const float*)d_in[0];
    const float* pos = (const float*)d_in[1];
    const float* W1  = (const float*)d_in[2];
    const float* b1  = (const float*)d_in[3];
    const float* W2  = (const float*)d_in[4];
    const float* b2  = (const float*)d_in[5];
    const float* sw  = (const float*)d_in[6];
    const void*  ei  = d_in[7];

    const int DH  = in_sizes[3];           // 256
    const int KC  = in_sizes[5];           // 50
    const int DIN = in_sizes[2] / DH;      // 512
    const int n   = in_sizes[0] / DIN;     // 50000
    const int E   = in_sizes[7] / 2;       // 800000

    char* p = (char*)d_ws;
    auto alloc = [&](size_t bytes) {
        char* r = p;
        p += (bytes + 255) & ~(size_t)255;
        return r;
    };
    int*   flag    = (int*)alloc(256);
    int*   es      = (int*)alloc((size_t)E * 4);
    int*   ed      = (int*)alloc((size_t)E * 4);
    int*   cnt     = (int*)alloc((size_t)n * 4);
    int*   cursor  = (int*)alloc((size_t)n * 4);
    int*   row_ptr = (int*)alloc(((size_t)n + 1) * 4);
    int*   btot    = (int*)alloc(1024 * 4);
    int*   csr     = (int*)alloc((size_t)E * 4);
    float* csr_nrm = (float*)alloc((size_t)E * 4);
    float* dinv    = (float*)alloc((size_t)n * 4);
    float* parts   = (float*)alloc(1024 * 4);
    unsigned short* Wt_hi = (unsigned short*)alloc((size_t)DIN * DH * 2);
    unsigned short* Wt_lo = (unsigned short*)alloc((size_t)DIN * DH * 2);
    f16*   W2t_hi  = (f16*)alloc((size_t)64 * DH * 2);
    f16*   W2t_lo  = (f16*)alloc((size_t)64 * DH * 2);
    f16*   h0      = (f16*)alloc((size_t)n * DH * 2);
    f16*   h       = (f16*)alloc((size_t)n * DH * 2);
    f16*   g       = (f16*)alloc((size_t)n * KC * 2);
    f16*   Sh      = (f16*)alloc((size_t)n * KC * 2);

    float* S    = (float*)d_out;
    float* Lout = S + (size_t)n * KC;

    const int nb = (n + 1023) / 1024;
    const int nk = DIN / G1_BK;

    hipMemsetAsync(cnt, 0, (size_t)n * 4, stream);
    detect_i64_kernel<<<1, 256, 0, stream>>>((const unsigned*)ei, flag);
    convert_edges_kernel<<<(2 * E + 255) / 256, 256, 0, stream>>>(ei, es, ed, cnt, E, flag);
    scan_block_kernel<<<nb, 1024, 0, stream>>>(cnt, row_ptr, btot, n);
    scan_tops_kernel<<<1, 1024, 0, stream>>>(btot, nb);
    scan_finalize_kernel<<<(n + 255) / 256, 256, 0, stream>>>(row_ptr, btot, cnt, cursor, dinv, n);
    scatter_kernel<<<(E + 255) / 256, 256, 0, stream>>>(es, ed, dinv, cursor, csr, csr_nrm, E);

    // weight prep
    wsplit_kernel<<<(DIN * DH + 255) / 256, 256, 0, stream>>>(W1, Wt_hi, Wt_lo, DIN, DH, nk);
    wsplit2_kernel<<<(64 * DH + 255) / 256, 256, 0, stream>>>(W2, W2t_hi, W2t_lo, DH, KC);

    // h0 = x @ W1   (MFMA bf16x3; glds staging; fp16 output)
    dim3 g1((n + G1_BM - 1) / G1_BM, DH / G1_BN);
    gemm1_mfma<<<g1, 256, 0, stream>>>(x, Wt_hi, Wt_lo, h0, n, DIN, DH);

    // h = relu(Ahat @ h0 + b1)  (f16 out)
    agg1_kernel<<<(int)(((size_t)n * 64 + 255) / 256), 256, 0, stream>>>(
        h0, dinv, row_ptr, csr, csr_nrm, b1, h, n);

    // g = h @ W2  (MFMA f16, no LDS)
    gemm2_mfma<<<(n + 63) / 64, 256, 0, stream>>>(h, W2t_hi, W2t_lo, g, n, DH, KC);

    // s = Ahat @ g + b2 ; S = softmax(s)  (+ fp16 shadow for loss)
    agg2_softmax_kernel<<<(int)(((size_t)n * 64 + 255) / 256), 256, 0, stream>>>(
        g, dinv, row_ptr, csr, csr_nrm, b2, S, Sh, n, KC);

    // L = sw * sum(d2 * <S_s, S_d>) / E
    loss_partial_kernel<<<1024, 256, 0, stream>>>(es, ed, pos, Sh, parts, E, KC);
    loss_final_kernel<<<1, 1024, 0, stream>>>(parts, sw, Lout, 1.0f / (float)E);
}

// Round 9
// 336.526 us; speedup vs baseline: 1.4015x; 1.0360x over previous
//
#include <hip/hip_runtime.h>
#include <math.h>

// ---------------------------------------------------------------------------
// DifferentiablePooling: 2-layer GCN + softmax + spatial loss
// Round 9: fuse agg1+gemm2 (h lives in LDS, never touches HBM); agg1 edge
//          loop unroll x4; Sh padded to 64 f16 + wide loss loads.
// ---------------------------------------------------------------------------

typedef __attribute__((ext_vector_type(8))) short bf16x8;
typedef __attribute__((ext_vector_type(4))) float f32x4;
typedef __attribute__((ext_vector_type(4))) unsigned int u32x4;
typedef _Float16 f16;
typedef __attribute__((ext_vector_type(2))) _Float16 f16x2;
typedef __attribute__((ext_vector_type(4))) _Float16 f16x4;
typedef __attribute__((ext_vector_type(8))) _Float16 f16x8;

__device__ inline unsigned short f32_to_bf16(float f) {
    unsigned u = __float_as_uint(f);
    unsigned r = u + 0x7FFFu + ((u >> 16) & 1u);   // RTNE; inputs are finite
    return (unsigned short)(r >> 16);
}
__device__ inline float bf16_to_f32(unsigned short h) {
    return __uint_as_float((unsigned)h << 16);
}

// async global->LDS, 16B per lane; lptr must be wave-uniform (HW adds lane*16)
__device__ inline void glds16(const void* g, void* l) {
    __builtin_amdgcn_global_load_lds(
        (const __attribute__((address_space(1))) unsigned int*)g,
        (__attribute__((address_space(3))) unsigned int*)l, 16, 0, 0);
}

// ---- edge dtype detection (int64 vs int32 on device) ----------------------
__global__ void detect_i64_kernel(const unsigned* __restrict__ w, int* __restrict__ flag) {
    __shared__ int red[256];
    int cnt = 0;
    for (int i = threadIdx.x; i < 4096; i += 256)
        cnt += (w[2 * i + 1] == 0u) ? 1 : 0;   // high words of int64 are 0
    red[threadIdx.x] = cnt;
    __syncthreads();
    for (int s = 128; s > 0; s >>= 1) {
        if ((int)threadIdx.x < s) red[threadIdx.x] += red[threadIdx.x + s];
        __syncthreads();
    }
    if (threadIdx.x == 0) *flag = (red[0] > 2048) ? 1 : 0;
}

// convert + fused degree count (atomicAdd on dst)
__global__ void convert_edges_kernel(const void* __restrict__ ei, int* __restrict__ es,
                                     int* __restrict__ ed, int* __restrict__ cnt,
                                     int E, const int* __restrict__ flag) {
    int idx = blockIdx.x * blockDim.x + threadIdx.x;
    if (idx >= 2 * E) return;
    int v;
    if (*flag) v = (int)((const long long*)ei)[idx];
    else       v = ((const int*)ei)[idx];
    if (idx < E) es[idx] = v;
    else { ed[idx - E] = v; atomicAdd(&cnt[v], 1); }
}

// hierarchical scan: (1) per-block inclusive scan -> row_ptr[i+1], block totals
__global__ __launch_bounds__(1024) void scan_block_kernel(const int* __restrict__ cnt,
        int* __restrict__ row_ptr, int* __restrict__ btot, int n) {
    __shared__ int buf[1024];
    int i = blockIdx.x * 1024 + threadIdx.x;
    buf[threadIdx.x] = (i < n) ? cnt[i] : 0;
    __syncthreads();
    for (int off = 1; off < 1024; off <<= 1) {
        int t = ((int)threadIdx.x >= off) ? buf[threadIdx.x - off] : 0;
        __syncthreads();
        buf[threadIdx.x] += t;
        __syncthreads();
    }
    if (i < n) row_ptr[i + 1] = buf[threadIdx.x];
    if (threadIdx.x == 1023) btot[blockIdx.x] = buf[1023];
}

// (2) inclusive scan of block totals (nb <= 1024)
__global__ __launch_bounds__(1024) void scan_tops_kernel(int* __restrict__ btot, int nb) {
    __shared__ int buf[1024];
    buf[threadIdx.x] = ((int)threadIdx.x < nb) ? btot[threadIdx.x] : 0;
    __syncthreads();
    for (int off = 1; off < 1024; off <<= 1) {
        int t = ((int)threadIdx.x >= off) ? buf[threadIdx.x - off] : 0;
        __syncthreads();
        buf[threadIdx.x] += t;
        __syncthreads();
    }
    if ((int)threadIdx.x < nb) btot[threadIdx.x] = buf[threadIdx.x];
}

// (3) add block offsets; emit cursor + dinv
__global__ void scan_finalize_kernel(int* __restrict__ row_ptr, const int* __restrict__ btot,
        const int* __restrict__ cnt, int* __restrict__ cursor, float* __restrict__ dinv, int n) {
    int i = blockIdx.x * blockDim.x + threadIdx.x;
    if (i >= n) return;
    int blk = i >> 10;
    int off = blk ? btot[blk - 1] : 0;
    int incl = row_ptr[i + 1] + off;
    row_ptr[i + 1] = incl;
    cursor[i] = incl - cnt[i];
    dinv[i] = rsqrtf((float)(cnt[i] + 1));   // +1 self loop
    if (i == 0) row_ptr[0] = 0;
}

// scatter + per-entry source norm (dinv[src]) for dependent-load-free agg
__global__ void scatter_kernel(const int* __restrict__ es, const int* __restrict__ ed,
                               const float* __restrict__ dinv, int* __restrict__ cursor,
                               int* __restrict__ csr_src, float* __restrict__ csr_nrm, int E) {
    int e = blockIdx.x * blockDim.x + threadIdx.x;
    if (e < E) {
        int s = es[e];
        int d = ed[e];
        int p = atomicAdd(&cursor[d], 1);
        csr_src[p] = s;
        csr_nrm[p] = dinv[s];
    }
}

// ---- W1 split + MFMA-native tiling ------------------------------------------
__global__ void wsplit_kernel(const float* __restrict__ W,
                              unsigned short* __restrict__ Th,
                              unsigned short* __restrict__ Tl, int K, int N, int nk) {
    int idx = blockIdx.x * 256 + threadIdx.x;
    if (idx >= K * N) return;
    int k = idx / N, n = idx % N;
    float f = W[idx];
    unsigned short h = f32_to_bf16(f);
    unsigned short l = f32_to_bf16(f - bf16_to_f32(h));
    int p = n >> 7, np = n & 127, t = k >> 5, kg = (k & 31) >> 3, ke = k & 7;
    size_t o = ((size_t)((p * nk + t) * 4 + kg) << 10) + np * 8 + ke;
    Th[o] = h;
    Tl[o] = l;
}

// ---- W2 split+transpose: W2[K][NC] f32 -> W2t_hi/lo[64][K] f16 (zero-padded)
__global__ void wsplit2_kernel(const float* __restrict__ W2,
                               f16* __restrict__ W2t_hi, f16* __restrict__ W2t_lo,
                               int K, int NC) {
    int idx = blockIdx.x * 256 + threadIdx.x;
    if (idx >= 64 * K) return;
    int n = idx / K, k = idx % K;
    float v = (n < NC) ? W2[(size_t)k * NC + n] : 0.f;
    f16 h = (f16)v;
    W2t_hi[idx] = h;
    W2t_lo[idx] = (f16)(v - (float)h);
}

// ---- GEMM1: h0[M,N](f16) = X[M,K](f32) @ W1[K,N] via MFMA bf16x3 ------------
#define G1_BM 128
#define G1_BN 128
#define G1_BK 32

__global__ __launch_bounds__(256) void gemm1_mfma(
        const float* __restrict__ X, const unsigned short* __restrict__ WtH,
        const unsigned short* __restrict__ WtL, f16* __restrict__ C,
        int M, int K, int N) {
    __shared__ __align__(16) unsigned char lds[32768];
    // [0,16384): A f32 swizzled; [16384,24576): Bh; [24576,32768): Bl

    const int tid  = threadIdx.x;
    const int lane = tid & 63;
    const int wave = tid >> 6;
    const int wm   = wave & 1;
    const int wn   = wave >> 1;
    const int m0   = blockIdx.x * G1_BM;
    const int pn   = blockIdx.y;          // 128-col panel index
    const int nk   = K / G1_BK;

    const float* Xbase[4];
    #pragma unroll
    for (int i = 0; i < 4; ++i) {
        int c   = i * 256 + tid;
        int row = c >> 3;
        int sl  = (c & 7) ^ (row & 7);    // pre-swizzled source slot
        int gr  = m0 + row;
        if (gr > M - 1) gr = M - 1;
        Xbase[i] = X + (size_t)gr * K + sl * 4;
    }
    const unsigned short* BhBase = WtH + ((size_t)pn * nk << 12) + (size_t)tid * 8;
    const unsigned short* BlBase = WtL + ((size_t)pn * nk << 12) + (size_t)tid * 8;

    f32x4 acc[4][4] = {};
    const int kq   = lane >> 4;
    const int frow = lane & 15;
    const int bOff = 16384 + (kq << 11) + ((wn * 64 + frow) << 4);

    for (int t = 0; t < nk; ++t) {
        const int k0 = t * G1_BK;
        #pragma unroll
        for (int i = 0; i < 4; ++i)
            glds16(Xbase[i] + k0, lds + i * 4096 + wave * 1024);
        const unsigned short* bh = BhBase + (size_t)t * 4096;
        const unsigned short* bl = BlBase + (size_t)t * 4096;
        glds16(bh,        lds + 16384 + wave * 1024);
        glds16(bh + 2048, lds + 20480 + wave * 1024);
        glds16(bl,        lds + 24576 + wave * 1024);
        glds16(bl + 2048, lds + 28672 + wave * 1024);
        __syncthreads();

        bf16x8 bhf[4], blf[4];
        #pragma unroll
        for (int nn = 0; nn < 4; ++nn) {
            bhf[nn] = *(const bf16x8*)(lds + bOff + nn * 256);
            blf[nn] = *(const bf16x8*)(lds + bOff + 8192 + nn * 256);
        }
        #pragma unroll
        for (int mm = 0; mm < 4; ++mm) {
            int ra = wm * 64 + mm * 16 + frow;
            int rb = ra << 7;
            int sw = (ra & 7) << 4;
            int s0 = kq << 1;
            f32x4 p0 = *(const f32x4*)(lds + rb + ((s0 << 4) ^ sw));
            f32x4 p1 = *(const f32x4*)(lds + rb + (((s0 + 1) << 4) ^ sw));
            float f[8] = {p0[0], p0[1], p0[2], p0[3], p1[0], p1[1], p1[2], p1[3]};
            u32x4 hv, lv;
            #pragma unroll
            for (int p = 0; p < 4; ++p) {
                unsigned b0 = __float_as_uint(f[2 * p]);
                unsigned b1 = __float_as_uint(f[2 * p + 1]);
                hv[p] = __builtin_amdgcn_perm(b1, b0, 0x07060302u);
                float l0 = f[2 * p]     - __uint_as_float(b0 & 0xFFFF0000u);
                float l1 = f[2 * p + 1] - __uint_as_float(b1 & 0xFFFF0000u);
                lv[p] = __builtin_amdgcn_perm(__float_as_uint(l1),
                                              __float_as_uint(l0), 0x07060302u);
            }
            union { u32x4 u; bf16x8 b; } ah, al;
            ah.u = hv; al.u = lv;
            #pragma unroll
            for (int nn = 0; nn < 4; ++nn)
                acc[mm][nn] = __builtin_amdgcn_mfma_f32_16x16x32_bf16(ah.b, bhf[nn], acc[mm][nn], 0, 0, 0);
            #pragma unroll
            for (int nn = 0; nn < 4; ++nn)
                acc[mm][nn] = __builtin_amdgcn_mfma_f32_16x16x32_bf16(ah.b, blf[nn], acc[mm][nn], 0, 0, 0);
            #pragma unroll
            for (int nn = 0; nn < 4; ++nn)
                acc[mm][nn] = __builtin_amdgcn_mfma_f32_16x16x32_bf16(al.b, bhf[nn], acc[mm][nn], 0, 0, 0);
        }
        __syncthreads();
    }

    const int n0 = pn * G1_BN;
    #pragma unroll
    for (int mm = 0; mm < 4; ++mm) {
        #pragma unroll
        for (int i = 0; i < 4; ++i) {
            int gr = m0 + wm * 64 + mm * 16 + kq * 4 + i;
            if (gr >= M) continue;
            #pragma unroll
            for (int nn = 0; nn < 4; ++nn) {
                int gc = n0 + wn * 64 + nn * 16 + frow;
                C[(size_t)gr * N + gc] = (f16)acc[mm][nn][i];
            }
        }
    }
}

// ---- fused agg1 + gemm2: h in LDS, g = relu(Ahat h0 + b1) @ W2 --------------
// block = 4 waves = 64 dst nodes. Phase 1: wave-per-node aggregation (x4
// unroll) -> LDS hs[64][264] (528B rows: phase-2 b128 reads 2-way = free).
// Phase 2: 64x64 MFMA f16 from LDS A + L2-resident W2t hi/lo. K = DH = 256.
__device__ inline float4 ld_h4(const f16x4* __restrict__ p) {
    f16x4 v = *p;
    return make_float4((float)v.x, (float)v.y, (float)v.z, (float)v.w);
}

__global__ __launch_bounds__(256) void agg1_gemm2_kernel(
        const f16* __restrict__ h0, const float* __restrict__ dinv,
        const int* __restrict__ row_ptr, const int* __restrict__ csr_src,
        const float* __restrict__ csr_nrm, const float* __restrict__ b1,
        const f16* __restrict__ W2t_hi, const f16* __restrict__ W2t_lo,
        f16* __restrict__ g, int n, int K, int KC) {
    __shared__ __align__(16) f16 hs[64][264];

    const int tid  = threadIdx.x;
    const int lane = tid & 63;
    const int wave = tid >> 6;
    const int base = blockIdx.x * 64;

    // ---- phase 1: aggregate 16 nodes per wave into LDS ----------------------
    const f16x4* h0v = (const f16x4*)h0;
    float4 bb = ((const float4*)b1)[lane];
    for (int i = 0; i < 16; ++i) {
        int wid = base + wave * 16 + i;
        f16x4 out = {0, 0, 0, 0};
        if (wid < n) {
            float di = dinv[wid];
            float4 v = ld_h4(&h0v[(size_t)wid * 64 + lane]);
            float self = di * di;
            float4 acc;
            acc.x = self * v.x; acc.y = self * v.y; acc.z = self * v.z; acc.w = self * v.w;
            int beg = row_ptr[wid], end = row_ptr[wid + 1];
            int j = beg;
            for (; j + 4 <= end; j += 4) {
                int s0 = csr_src[j],     s1 = csr_src[j + 1];
                int s2 = csr_src[j + 2], s3 = csr_src[j + 3];
                float n0 = csr_nrm[j] * di,     n1 = csr_nrm[j + 1] * di;
                float n2 = csr_nrm[j + 2] * di, n3 = csr_nrm[j + 3] * di;
                float4 u0 = ld_h4(&h0v[(size_t)s0 * 64 + lane]);
                float4 u1 = ld_h4(&h0v[(size_t)s1 * 64 + lane]);
                float4 u2 = ld_h4(&h0v[(size_t)s2 * 64 + lane]);
                float4 u3 = ld_h4(&h0v[(size_t)s3 * 64 + lane]);
                acc.x = fmaf(n0, u0.x, acc.x); acc.y = fmaf(n0, u0.y, acc.y);
                acc.z = fmaf(n0, u0.z, acc.z); acc.w = fmaf(n0, u0.w, acc.w);
                acc.x = fmaf(n1, u1.x, acc.x); acc.y = fmaf(n1, u1.y, acc.y);
                acc.z = fmaf(n1, u1.z, acc.z); acc.w = fmaf(n1, u1.w, acc.w);
                acc.x = fmaf(n2, u2.x, acc.x); acc.y = fmaf(n2, u2.y, acc.y);
                acc.z = fmaf(n2, u2.z, acc.z); acc.w = fmaf(n2, u2.w, acc.w);
                acc.x = fmaf(n3, u3.x, acc.x); acc.y = fmaf(n3, u3.y, acc.y);
                acc.z = fmaf(n3, u3.z, acc.z); acc.w = fmaf(n3, u3.w, acc.w);
            }
            for (; j < end; ++j) {
                int s0 = csr_src[j];
                float n0 = csr_nrm[j] * di;
                float4 u0 = ld_h4(&h0v[(size_t)s0 * 64 + lane]);
                acc.x = fmaf(n0, u0.x, acc.x); acc.y = fmaf(n0, u0.y, acc.y);
                acc.z = fmaf(n0, u0.z, acc.z); acc.w = fmaf(n0, u0.w, acc.w);
            }
            out.x = (f16)fmaxf(acc.x + bb.x, 0.f);
            out.y = (f16)fmaxf(acc.y + bb.y, 0.f);
            out.z = (f16)fmaxf(acc.z + bb.z, 0.f);
            out.w = (f16)fmaxf(acc.w + bb.w, 0.f);
        }
        *(f16x4*)&hs[wave * 16 + i][lane * 4] = out;
    }
    __syncthreads();

    // ---- phase 2: g[64 x KC] = hs[64 x K] @ W2t^T (hi+lo), MFMA f16 ---------
    const int wm   = wave & 1;
    const int wn   = wave >> 1;
    const int kq   = lane >> 4;
    const int frow = lane & 15;
    const int koff = kq * 8;

    f32x4 acc2[2][2] = {};
    const f16* bh_base[2];
    const f16* bl_base[2];
    #pragma unroll
    for (int nn = 0; nn < 2; ++nn) {
        int r = wn * 32 + nn * 16 + frow;
        bh_base[nn] = W2t_hi + (size_t)r * K + koff;
        bl_base[nn] = W2t_lo + (size_t)r * K + koff;
    }

    for (int t = 0; t < K / 32; ++t) {
        const int kk = t * 32;
        f16x8 a[2], bh[2], bl[2];
        #pragma unroll
        for (int mm = 0; mm < 2; ++mm)
            a[mm] = *(const f16x8*)&hs[wm * 32 + mm * 16 + frow][kk + koff];
        #pragma unroll
        for (int nn = 0; nn < 2; ++nn) {
            bh[nn] = *(const f16x8*)(bh_base[nn] + kk);
            bl[nn] = *(const f16x8*)(bl_base[nn] + kk);
        }
        #pragma unroll
        for (int mm = 0; mm < 2; ++mm)
            #pragma unroll
            for (int nn = 0; nn < 2; ++nn) {
                acc2[mm][nn] = __builtin_amdgcn_mfma_f32_16x16x32_f16(a[mm], bh[nn], acc2[mm][nn], 0, 0, 0);
                acc2[mm][nn] = __builtin_amdgcn_mfma_f32_16x16x32_f16(a[mm], bl[nn], acc2[mm][nn], 0, 0, 0);
            }
    }

    #pragma unroll
    for (int mm = 0; mm < 2; ++mm) {
        #pragma unroll
        for (int i = 0; i < 4; ++i) {
            int gr = base + wm * 32 + mm * 16 + kq * 4 + i;
            if (gr >= n) continue;
            #pragma unroll
            for (int nn = 0; nn < 2; ++nn) {
                int gc = wn * 32 + nn * 16 + frow;
                if (gc < KC) g[(size_t)gr * KC + gc] = (f16)acc2[mm][nn][i];
            }
        }
    }
}

// ---- layer-2 aggregation + softmax: 4-way unroll, csr_nrm -------------------
// Sh padded to stride 64 f16 (16B-aligned rows for wide loss loads)
__global__ __launch_bounds__(256) void agg2_softmax_kernel(const f16* __restrict__ g,
        const float* __restrict__ dinv, const int* __restrict__ row_ptr,
        const int* __restrict__ csr_src, const float* __restrict__ csr_nrm,
        const float* __restrict__ b2, float* __restrict__ S, f16* __restrict__ Sh,
        int n, int KC) {
    int wid = (int)((blockIdx.x * (size_t)blockDim.x + threadIdx.x) >> 6);
    int lane = threadIdx.x & 63;
    if (wid >= n) return;
    bool act = lane < KC;
    size_t gidx = act ? (size_t)lane : 0;
    float di = dinv[wid];
    float a0 = 0.f, a1 = 0.f, a2 = 0.f, a3 = 0.f;
    if (act) a0 = di * di * (float)g[(size_t)wid * KC + lane];
    int beg = row_ptr[wid], end = row_ptr[wid + 1];
    int j = beg;
    for (; j + 4 <= end; j += 4) {
        int s0 = csr_src[j], s1 = csr_src[j + 1], s2 = csr_src[j + 2], s3 = csr_src[j + 3];
        float n0 = csr_nrm[j]     * di;
        float n1 = csr_nrm[j + 1] * di;
        float n2 = csr_nrm[j + 2] * di;
        float n3 = csr_nrm[j + 3] * di;
        float g0 = (float)g[(size_t)s0 * KC + gidx];
        float g1 = (float)g[(size_t)s1 * KC + gidx];
        float g2 = (float)g[(size_t)s2 * KC + gidx];
        float g3 = (float)g[(size_t)s3 * KC + gidx];
        a0 = fmaf(n0, g0, a0);
        a1 = fmaf(n1, g1, a1);
        a2 = fmaf(n2, g2, a2);
        a3 = fmaf(n3, g3, a3);
    }
    for (; j < end; ++j) {
        int s0 = csr_src[j];
        float n0 = csr_nrm[j] * di;
        a0 = fmaf(n0, (float)g[(size_t)s0 * KC + gidx], a0);
    }
    float acc = (a0 + a1) + (a2 + a3);
    float val = act ? (acc + b2[lane]) : -INFINITY;
    float m = val;
    #pragma unroll
    for (int o = 32; o > 0; o >>= 1) m = fmaxf(m, __shfl_xor(m, o));
    float e = act ? expf(val - m) : 0.f;
    float ssum = e;
    #pragma unroll
    for (int o = 32; o > 0; o >>= 1) ssum += __shfl_xor(ssum, o);
    if (lane < 64) {
        float sv = act ? (e / ssum) : 0.f;
        if (act) S[(size_t)wid * KC + lane] = sv;
        Sh[(size_t)wid * 64 + lane] = (f16)sv;   // padded row (zeros 50..63)
    }
}

// ---- spatial loss on padded f16 S-shadow (stride 64), wide loads ------------
__global__ __launch_bounds__(256) void loss_partial_kernel(const int* __restrict__ es,
        const int* __restrict__ ed, const float* __restrict__ pos,
        const f16* __restrict__ Sh, float* __restrict__ parts, int E) {
    float local = 0.f;
    int stride = gridDim.x * blockDim.x;
    for (int e = blockIdx.x * blockDim.x + threadIdx.x; e < E; e += stride) {
        int s = es[e], d = ed[e];
        float2 ps = ((const float2*)pos)[s];
        float2 pd = ((const float2*)pos)[d];
        float dx = ps.x - pd.x, dy = ps.y - pd.y;
        float d2 = dx * dx + dy * dy;
        const f16x8* Sa = (const f16x8*)(Sh + (size_t)s * 64);
        const f16x8* Sb = (const f16x8*)(Sh + (size_t)d * 64);
        float dot = 0.f;
        #pragma unroll
        for (int q = 0; q < 7; ++q) {            // 56 lanes cover 50 + zero pad
            f16x8 a = Sa[q], b = Sb[q];
            #pragma unroll
            for (int k = 0; k < 8; ++k)
                dot = fmaf((float)a[k], (float)b[k], dot);
        }
        local = fmaf(d2, dot, local);
    }
    __shared__ float red[256];
    red[threadIdx.x] = local;
    __syncthreads();
    for (int s = 128; s > 0; s >>= 1) {
        if ((int)threadIdx.x < s) red[threadIdx.x] += red[threadIdx.x + s];
        __syncthreads();
    }
    if (threadIdx.x == 0) parts[blockIdx.x] = red[0];
}

__global__ __launch_bounds__(1024) void loss_final_kernel(const float* __restrict__ parts,
        const float* __restrict__ sw, float* __restrict__ out, float invE) {
    __shared__ float red[1024];
    red[threadIdx.x] = parts[threadIdx.x];
    __syncthreads();
    for (int s = 512; s > 0; s >>= 1) {
        if ((int)threadIdx.x < s) red[threadIdx.x] += red[threadIdx.x + s];
        __syncthreads();
    }
    if (threadIdx.x == 0) out[0] = sw[0] * red[0] * invE;
}

// ---------------------------------------------------------------------------
extern "C" void kernel_launch(void* const* d_in, const int* in_sizes, int n_in,
                              void* d_out, int out_size, void* d_ws, size_t ws_size,
                              hipStream_t stream) {
    const float* x   = (const float*)d_in[0];
    const float* pos = (const float*)d_in[1];
    const float* W1  = (const float*)d_in[2];
    const float* b1  = (const float*)d_in[3];
    const float* W2  = (const float*)d_in[4];
    const float* b2  = (const float*)d_in[5];
    const float* sw  = (const float*)d_in[6];
    const void*  ei  = d_in[7];

    const int DH  = in_sizes[3];           // 256
    const int KC  = in_sizes[5];           // 50
    const int DIN = in_sizes[2] / DH;      // 512
    const int n   = in_sizes[0] / DIN;     // 50000
    const int E   = in_sizes[7] / 2;       // 800000

    char* p = (char*)d_ws;
    auto alloc = [&](size_t bytes) {
        char* r = p;
        p += (bytes + 255) & ~(size_t)255;
        return r;
    };
    int*   flag    = (int*)alloc(256);
    int*   es      = (int*)alloc((size_t)E * 4);
    int*   ed      = (int*)alloc((size_t)E * 4);
    int*   cnt     = (int*)alloc((size_t)n * 4);
    int*   cursor  = (int*)alloc((size_t)n * 4);
    int*   row_ptr = (int*)alloc(((size_t)n + 1) * 4);
    int*   btot    = (int*)alloc(1024 * 4);
    int*   csr     = (int*)alloc((size_t)E * 4);
    float* csr_nrm = (float*)alloc((size_t)E * 4);
    float* dinv    = (float*)alloc((size_t)n * 4);
    float* parts   = (float*)alloc(1024 * 4);
    unsigned short* Wt_hi = (unsigned short*)alloc((size_t)DIN * DH * 2);
    unsigned short* Wt_lo = (unsigned short*)alloc((size_t)DIN * DH * 2);
    f16*   W2t_hi  = (f16*)alloc((size_t)64 * DH * 2);
    f16*   W2t_lo  = (f16*)alloc((size_t)64 * DH * 2);
    f16*   h0      = (f16*)alloc((size_t)n * DH * 2);
    f16*   g       = (f16*)alloc((size_t)n * KC * 2);
    f16*   Sh      = (f16*)alloc((size_t)n * 64 * 2);

    float* S    = (float*)d_out;
    float* Lout = S + (size_t)n * KC;

    const int nb = (n + 1023) / 1024;
    const int nk = DIN / G1_BK;

    hipMemsetAsync(cnt, 0, (size_t)n * 4, stream);
    detect_i64_kernel<<<1, 256, 0, stream>>>((const unsigned*)ei, flag);
    convert_edges_kernel<<<(2 * E + 255) / 256, 256, 0, stream>>>(ei, es, ed, cnt, E, flag);
    scan_block_kernel<<<nb, 1024, 0, stream>>>(cnt, row_ptr, btot, n);
    scan_tops_kernel<<<1, 1024, 0, stream>>>(btot, nb);
    scan_finalize_kernel<<<(n + 255) / 256, 256, 0, stream>>>(row_ptr, btot, cnt, cursor, dinv, n);
    scatter_kernel<<<(E + 255) / 256, 256, 0, stream>>>(es, ed, dinv, cursor, csr, csr_nrm, E);

    // weight prep
    wsplit_kernel<<<(DIN * DH + 255) / 256, 256, 0, stream>>>(W1, Wt_hi, Wt_lo, DIN, DH, nk);
    wsplit2_kernel<<<(64 * DH + 255) / 256, 256, 0, stream>>>(W2, W2t_hi, W2t_lo, DH, KC);

    // h0 = x @ W1   (MFMA bf16x3; glds staging; fp16 output)
    dim3 g1((n + G1_BM - 1) / G1_BM, DH / G1_BN);
    gemm1_mfma<<<g1, 256, 0, stream>>>(x, Wt_hi, Wt_lo, h0, n, DIN, DH);

    // g = relu(Ahat @ h0 + b1) @ W2  (fused: h lives in LDS only)
    agg1_gemm2_kernel<<<(n + 63) / 64, 256, 0, stream>>>(
        h0, dinv, row_ptr, csr, csr_nrm, b1, W2t_hi, W2t_lo, g, n, DH, KC);

    // s = Ahat @ g + b2 ; S = softmax(s)  (+ padded fp16 shadow for loss)
    agg2_softmax_kernel<<<(int)(((size_t)n * 64 + 255) / 256), 256, 0, stream>>>(
        g, dinv, row_ptr, csr, csr_nrm, b2, S, Sh, n, KC);

    // L = sw * sum(d2 * <S_s, S_d>) / E
    loss_partial_kernel<<<1024, 256, 0, stream>>>(es, ed, pos, Sh, parts, E);
    loss_final_kernel<<<1, 1024, 0, stream>>>(parts, sw, Lout, 1.0f / (float)E);
}

// Round 10
// 330.064 us; speedup vs baseline: 1.4289x; 1.0196x over previous
//
#include <hip/hip_runtime.h>
#include <math.h>

// ---------------------------------------------------------------------------
// DifferentiablePooling: 2-layer GCN + softmax + spatial loss
// Round 10: fused agg1+gemm2 re-tiled to 32 nodes/block (grid 2x, LDS 16.9KB)
//           to restore gather occupancy lost in round 9.
// ---------------------------------------------------------------------------

typedef __attribute__((ext_vector_type(8))) short bf16x8;
typedef __attribute__((ext_vector_type(4))) float f32x4;
typedef __attribute__((ext_vector_type(4))) unsigned int u32x4;
typedef _Float16 f16;
typedef __attribute__((ext_vector_type(2))) _Float16 f16x2;
typedef __attribute__((ext_vector_type(4))) _Float16 f16x4;
typedef __attribute__((ext_vector_type(8))) _Float16 f16x8;

__device__ inline unsigned short f32_to_bf16(float f) {
    unsigned u = __float_as_uint(f);
    unsigned r = u + 0x7FFFu + ((u >> 16) & 1u);   // RTNE; inputs are finite
    return (unsigned short)(r >> 16);
}
__device__ inline float bf16_to_f32(unsigned short h) {
    return __uint_as_float((unsigned)h << 16);
}

// async global->LDS, 16B per lane; lptr must be wave-uniform (HW adds lane*16)
__device__ inline void glds16(const void* g, void* l) {
    __builtin_amdgcn_global_load_lds(
        (const __attribute__((address_space(1))) unsigned int*)g,
        (__attribute__((address_space(3))) unsigned int*)l, 16, 0, 0);
}

// ---- edge dtype detection (int64 vs int32 on device) ----------------------
__global__ void detect_i64_kernel(const unsigned* __restrict__ w, int* __restrict__ flag) {
    __shared__ int red[256];
    int cnt = 0;
    for (int i = threadIdx.x; i < 4096; i += 256)
        cnt += (w[2 * i + 1] == 0u) ? 1 : 0;   // high words of int64 are 0
    red[threadIdx.x] = cnt;
    __syncthreads();
    for (int s = 128; s > 0; s >>= 1) {
        if ((int)threadIdx.x < s) red[threadIdx.x] += red[threadIdx.x + s];
        __syncthreads();
    }
    if (threadIdx.x == 0) *flag = (red[0] > 2048) ? 1 : 0;
}

// convert + fused degree count (atomicAdd on dst)
__global__ void convert_edges_kernel(const void* __restrict__ ei, int* __restrict__ es,
                                     int* __restrict__ ed, int* __restrict__ cnt,
                                     int E, const int* __restrict__ flag) {
    int idx = blockIdx.x * blockDim.x + threadIdx.x;
    if (idx >= 2 * E) return;
    int v;
    if (*flag) v = (int)((const long long*)ei)[idx];
    else       v = ((const int*)ei)[idx];
    if (idx < E) es[idx] = v;
    else { ed[idx - E] = v; atomicAdd(&cnt[v], 1); }
}

// hierarchical scan: (1) per-block inclusive scan -> row_ptr[i+1], block totals
__global__ __launch_bounds__(1024) void scan_block_kernel(const int* __restrict__ cnt,
        int* __restrict__ row_ptr, int* __restrict__ btot, int n) {
    __shared__ int buf[1024];
    int i = blockIdx.x * 1024 + threadIdx.x;
    buf[threadIdx.x] = (i < n) ? cnt[i] : 0;
    __syncthreads();
    for (int off = 1; off < 1024; off <<= 1) {
        int t = ((int)threadIdx.x >= off) ? buf[threadIdx.x - off] : 0;
        __syncthreads();
        buf[threadIdx.x] += t;
        __syncthreads();
    }
    if (i < n) row_ptr[i + 1] = buf[threadIdx.x];
    if (threadIdx.x == 1023) btot[blockIdx.x] = buf[1023];
}

// (2) inclusive scan of block totals (nb <= 1024)
__global__ __launch_bounds__(1024) void scan_tops_kernel(int* __restrict__ btot, int nb) {
    __shared__ int buf[1024];
    buf[threadIdx.x] = ((int)threadIdx.x < nb) ? btot[threadIdx.x] : 0;
    __syncthreads();
    for (int off = 1; off < 1024; off <<= 1) {
        int t = ((int)threadIdx.x >= off) ? buf[threadIdx.x - off] : 0;
        __syncthreads();
        buf[threadIdx.x] += t;
        __syncthreads();
    }
    if ((int)threadIdx.x < nb) btot[threadIdx.x] = buf[threadIdx.x];
}

// (3) add block offsets; emit cursor + dinv
__global__ void scan_finalize_kernel(int* __restrict__ row_ptr, const int* __restrict__ btot,
        const int* __restrict__ cnt, int* __restrict__ cursor, float* __restrict__ dinv, int n) {
    int i = blockIdx.x * blockDim.x + threadIdx.x;
    if (i >= n) return;
    int blk = i >> 10;
    int off = blk ? btot[blk - 1] : 0;
    int incl = row_ptr[i + 1] + off;
    row_ptr[i + 1] = incl;
    cursor[i] = incl - cnt[i];
    dinv[i] = rsqrtf((float)(cnt[i] + 1));   // +1 self loop
    if (i == 0) row_ptr[0] = 0;
}

// scatter + per-entry source norm (dinv[src]) for dependent-load-free agg
__global__ void scatter_kernel(const int* __restrict__ es, const int* __restrict__ ed,
                               const float* __restrict__ dinv, int* __restrict__ cursor,
                               int* __restrict__ csr_src, float* __restrict__ csr_nrm, int E) {
    int e = blockIdx.x * blockDim.x + threadIdx.x;
    if (e < E) {
        int s = es[e];
        int d = ed[e];
        int p = atomicAdd(&cursor[d], 1);
        csr_src[p] = s;
        csr_nrm[p] = dinv[s];
    }
}

// ---- W1 split + MFMA-native tiling ------------------------------------------
__global__ void wsplit_kernel(const float* __restrict__ W,
                              unsigned short* __restrict__ Th,
                              unsigned short* __restrict__ Tl, int K, int N, int nk) {
    int idx = blockIdx.x * 256 + threadIdx.x;
    if (idx >= K * N) return;
    int k = idx / N, n = idx % N;
    float f = W[idx];
    unsigned short h = f32_to_bf16(f);
    unsigned short l = f32_to_bf16(f - bf16_to_f32(h));
    int p = n >> 7, np = n & 127, t = k >> 5, kg = (k & 31) >> 3, ke = k & 7;
    size_t o = ((size_t)((p * nk + t) * 4 + kg) << 10) + np * 8 + ke;
    Th[o] = h;
    Tl[o] = l;
}

// ---- W2 split+transpose: W2[K][NC] f32 -> W2t_hi/lo[64][K] f16 (zero-padded)
__global__ void wsplit2_kernel(const float* __restrict__ W2,
                               f16* __restrict__ W2t_hi, f16* __restrict__ W2t_lo,
                               int K, int NC) {
    int idx = blockIdx.x * 256 + threadIdx.x;
    if (idx >= 64 * K) return;
    int n = idx / K, k = idx % K;
    float v = (n < NC) ? W2[(size_t)k * NC + n] : 0.f;
    f16 h = (f16)v;
    W2t_hi[idx] = h;
    W2t_lo[idx] = (f16)(v - (float)h);
}

// ---- GEMM1: h0[M,N](f16) = X[M,K](f32) @ W1[K,N] via MFMA bf16x3 ------------
#define G1_BM 128
#define G1_BN 128
#define G1_BK 32

__global__ __launch_bounds__(256) void gemm1_mfma(
        const float* __restrict__ X, const unsigned short* __restrict__ WtH,
        const unsigned short* __restrict__ WtL, f16* __restrict__ C,
        int M, int K, int N) {
    __shared__ __align__(16) unsigned char lds[32768];
    // [0,16384): A f32 swizzled; [16384,24576): Bh; [24576,32768): Bl

    const int tid  = threadIdx.x;
    const int lane = tid & 63;
    const int wave = tid >> 6;
    const int wm   = wave & 1;
    const int wn   = wave >> 1;
    const int m0   = blockIdx.x * G1_BM;
    const int pn   = blockIdx.y;          // 128-col panel index
    const int nk   = K / G1_BK;

    const float* Xbase[4];
    #pragma unroll
    for (int i = 0; i < 4; ++i) {
        int c   = i * 256 + tid;
        int row = c >> 3;
        int sl  = (c & 7) ^ (row & 7);    // pre-swizzled source slot
        int gr  = m0 + row;
        if (gr > M - 1) gr = M - 1;
        Xbase[i] = X + (size_t)gr * K + sl * 4;
    }
    const unsigned short* BhBase = WtH + ((size_t)pn * nk << 12) + (size_t)tid * 8;
    const unsigned short* BlBase = WtL + ((size_t)pn * nk << 12) + (size_t)tid * 8;

    f32x4 acc[4][4] = {};
    const int kq   = lane >> 4;
    const int frow = lane & 15;
    const int bOff = 16384 + (kq << 11) + ((wn * 64 + frow) << 4);

    for (int t = 0; t < nk; ++t) {
        const int k0 = t * G1_BK;
        #pragma unroll
        for (int i = 0; i < 4; ++i)
            glds16(Xbase[i] + k0, lds + i * 4096 + wave * 1024);
        const unsigned short* bh = BhBase + (size_t)t * 4096;
        const unsigned short* bl = BlBase + (size_t)t * 4096;
        glds16(bh,        lds + 16384 + wave * 1024);
        glds16(bh + 2048, lds + 20480 + wave * 1024);
        glds16(bl,        lds + 24576 + wave * 1024);
        glds16(bl + 2048, lds + 28672 + wave * 1024);
        __syncthreads();

        bf16x8 bhf[4], blf[4];
        #pragma unroll
        for (int nn = 0; nn < 4; ++nn) {
            bhf[nn] = *(const bf16x8*)(lds + bOff + nn * 256);
            blf[nn] = *(const bf16x8*)(lds + bOff + 8192 + nn * 256);
        }
        #pragma unroll
        for (int mm = 0; mm < 4; ++mm) {
            int ra = wm * 64 + mm * 16 + frow;
            int rb = ra << 7;
            int sw = (ra & 7) << 4;
            int s0 = kq << 1;
            f32x4 p0 = *(const f32x4*)(lds + rb + ((s0 << 4) ^ sw));
            f32x4 p1 = *(const f32x4*)(lds + rb + (((s0 + 1) << 4) ^ sw));
            float f[8] = {p0[0], p0[1], p0[2], p0[3], p1[0], p1[1], p1[2], p1[3]};
            u32x4 hv, lv;
            #pragma unroll
            for (int p = 0; p < 4; ++p) {
                unsigned b0 = __float_as_uint(f[2 * p]);
                unsigned b1 = __float_as_uint(f[2 * p + 1]);
                hv[p] = __builtin_amdgcn_perm(b1, b0, 0x07060302u);
                float l0 = f[2 * p]     - __uint_as_float(b0 & 0xFFFF0000u);
                float l1 = f[2 * p + 1] - __uint_as_float(b1 & 0xFFFF0000u);
                lv[p] = __builtin_amdgcn_perm(__float_as_uint(l1),
                                              __float_as_uint(l0), 0x07060302u);
            }
            union { u32x4 u; bf16x8 b; } ah, al;
            ah.u = hv; al.u = lv;
            #pragma unroll
            for (int nn = 0; nn < 4; ++nn)
                acc[mm][nn] = __builtin_amdgcn_mfma_f32_16x16x32_bf16(ah.b, bhf[nn], acc[mm][nn], 0, 0, 0);
            #pragma unroll
            for (int nn = 0; nn < 4; ++nn)
                acc[mm][nn] = __builtin_amdgcn_mfma_f32_16x16x32_bf16(ah.b, blf[nn], acc[mm][nn], 0, 0, 0);
            #pragma unroll
            for (int nn = 0; nn < 4; ++nn)
                acc[mm][nn] = __builtin_amdgcn_mfma_f32_16x16x32_bf16(al.b, bhf[nn], acc[mm][nn], 0, 0, 0);
        }
        __syncthreads();
    }

    const int n0 = pn * G1_BN;
    #pragma unroll
    for (int mm = 0; mm < 4; ++mm) {
        #pragma unroll
        for (int i = 0; i < 4; ++i) {
            int gr = m0 + wm * 64 + mm * 16 + kq * 4 + i;
            if (gr >= M) continue;
            #pragma unroll
            for (int nn = 0; nn < 4; ++nn) {
                int gc = n0 + wn * 64 + nn * 16 + frow;
                C[(size_t)gr * N + gc] = (f16)acc[mm][nn][i];
            }
        }
    }
}

// ---- fused agg1 + gemm2: 32 nodes/block, h in LDS only ----------------------
// 4 waves, phase 1: wave aggregates 8 nodes (x4 unroll) -> hs[32][264].
// phase 2: 32x64 MFMA f16 tile: wave = 16 rows x 32 cols (acc[2]).
__device__ inline float4 ld_h4(const f16x4* __restrict__ p) {
    f16x4 v = *p;
    return make_float4((float)v.x, (float)v.y, (float)v.z, (float)v.w);
}

__global__ __launch_bounds__(256) void agg1_gemm2_kernel(
        const f16* __restrict__ h0, const float* __restrict__ dinv,
        const int* __restrict__ row_ptr, const int* __restrict__ csr_src,
        const float* __restrict__ csr_nrm, const float* __restrict__ b1,
        const f16* __restrict__ W2t_hi, const f16* __restrict__ W2t_lo,
        f16* __restrict__ g, int n, int K, int KC) {
    __shared__ __align__(16) f16 hs[32][264];

    const int tid  = threadIdx.x;
    const int lane = tid & 63;
    const int wave = tid >> 6;
    const int base = blockIdx.x * 32;

    // ---- phase 1: aggregate 8 nodes per wave into LDS -----------------------
    const f16x4* h0v = (const f16x4*)h0;
    float4 bb = ((const float4*)b1)[lane];
    for (int i = 0; i < 8; ++i) {
        int wid = base + wave * 8 + i;
        f16x4 out = {0, 0, 0, 0};
        if (wid < n) {
            float di = dinv[wid];
            float4 v = ld_h4(&h0v[(size_t)wid * 64 + lane]);
            float self = di * di;
            float4 acc;
            acc.x = self * v.x; acc.y = self * v.y; acc.z = self * v.z; acc.w = self * v.w;
            int beg = row_ptr[wid], end = row_ptr[wid + 1];
            int j = beg;
            for (; j + 4 <= end; j += 4) {
                int s0 = csr_src[j],     s1 = csr_src[j + 1];
                int s2 = csr_src[j + 2], s3 = csr_src[j + 3];
                float n0 = csr_nrm[j] * di,     n1 = csr_nrm[j + 1] * di;
                float n2 = csr_nrm[j + 2] * di, n3 = csr_nrm[j + 3] * di;
                float4 u0 = ld_h4(&h0v[(size_t)s0 * 64 + lane]);
                float4 u1 = ld_h4(&h0v[(size_t)s1 * 64 + lane]);
                float4 u2 = ld_h4(&h0v[(size_t)s2 * 64 + lane]);
                float4 u3 = ld_h4(&h0v[(size_t)s3 * 64 + lane]);
                acc.x = fmaf(n0, u0.x, acc.x); acc.y = fmaf(n0, u0.y, acc.y);
                acc.z = fmaf(n0, u0.z, acc.z); acc.w = fmaf(n0, u0.w, acc.w);
                acc.x = fmaf(n1, u1.x, acc.x); acc.y = fmaf(n1, u1.y, acc.y);
                acc.z = fmaf(n1, u1.z, acc.z); acc.w = fmaf(n1, u1.w, acc.w);
                acc.x = fmaf(n2, u2.x, acc.x); acc.y = fmaf(n2, u2.y, acc.y);
                acc.z = fmaf(n2, u2.z, acc.z); acc.w = fmaf(n2, u2.w, acc.w);
                acc.x = fmaf(n3, u3.x, acc.x); acc.y = fmaf(n3, u3.y, acc.y);
                acc.z = fmaf(n3, u3.z, acc.z); acc.w = fmaf(n3, u3.w, acc.w);
            }
            for (; j < end; ++j) {
                int s0 = csr_src[j];
                float n0 = csr_nrm[j] * di;
                float4 u0 = ld_h4(&h0v[(size_t)s0 * 64 + lane]);
                acc.x = fmaf(n0, u0.x, acc.x); acc.y = fmaf(n0, u0.y, acc.y);
                acc.z = fmaf(n0, u0.z, acc.z); acc.w = fmaf(n0, u0.w, acc.w);
            }
            out.x = (f16)fmaxf(acc.x + bb.x, 0.f);
            out.y = (f16)fmaxf(acc.y + bb.y, 0.f);
            out.z = (f16)fmaxf(acc.z + bb.z, 0.f);
            out.w = (f16)fmaxf(acc.w + bb.w, 0.f);
        }
        *(f16x4*)&hs[wave * 8 + i][lane * 4] = out;
    }
    __syncthreads();

    // ---- phase 2: g[32 x KC] = hs[32 x K] @ W2t^T (hi+lo), MFMA f16 ---------
    const int wm   = wave & 1;       // 16-row strip
    const int wn   = wave >> 1;      // 32-col strip
    const int kq   = lane >> 4;
    const int frow = lane & 15;
    const int koff = kq * 8;

    f32x4 acc2[2] = {};
    const f16* bh_base[2];
    const f16* bl_base[2];
    #pragma unroll
    for (int nn = 0; nn < 2; ++nn) {
        int r = wn * 32 + nn * 16 + frow;
        bh_base[nn] = W2t_hi + (size_t)r * K + koff;
        bl_base[nn] = W2t_lo + (size_t)r * K + koff;
    }

    for (int t = 0; t < K / 32; ++t) {
        const int kk = t * 32;
        f16x8 a = *(const f16x8*)&hs[wm * 16 + frow][kk + koff];
        #pragma unroll
        for (int nn = 0; nn < 2; ++nn) {
            f16x8 bh = *(const f16x8*)(bh_base[nn] + kk);
            f16x8 bl = *(const f16x8*)(bl_base[nn] + kk);
            acc2[nn] = __builtin_amdgcn_mfma_f32_16x16x32_f16(a, bh, acc2[nn], 0, 0, 0);
            acc2[nn] = __builtin_amdgcn_mfma_f32_16x16x32_f16(a, bl, acc2[nn], 0, 0, 0);
        }
    }

    #pragma unroll
    for (int i = 0; i < 4; ++i) {
        int gr = base + wm * 16 + kq * 4 + i;
        if (gr >= n) continue;
        #pragma unroll
        for (int nn = 0; nn < 2; ++nn) {
            int gc = wn * 32 + nn * 16 + frow;
            if (gc < KC) g[(size_t)gr * KC + gc] = (f16)acc2[nn][i];
        }
    }
}

// ---- layer-2 aggregation + softmax: 4-way unroll, csr_nrm -------------------
// Sh padded to stride 64 f16 (16B-aligned rows for wide loss loads)
__global__ __launch_bounds__(256) void agg2_softmax_kernel(const f16* __restrict__ g,
        const float* __restrict__ dinv, const int* __restrict__ row_ptr,
        const int* __restrict__ csr_src, const float* __restrict__ csr_nrm,
        const float* __restrict__ b2, float* __restrict__ S, f16* __restrict__ Sh,
        int n, int KC) {
    int wid = (int)((blockIdx.x * (size_t)blockDim.x + threadIdx.x) >> 6);
    int lane = threadIdx.x & 63;
    if (wid >= n) return;
    bool act = lane < KC;
    size_t gidx = act ? (size_t)lane : 0;
    float di = dinv[wid];
    float a0 = 0.f, a1 = 0.f, a2 = 0.f, a3 = 0.f;
    if (act) a0 = di * di * (float)g[(size_t)wid * KC + lane];
    int beg = row_ptr[wid], end = row_ptr[wid + 1];
    int j = beg;
    for (; j + 4 <= end; j += 4) {
        int s0 = csr_src[j], s1 = csr_src[j + 1], s2 = csr_src[j + 2], s3 = csr_src[j + 3];
        float n0 = csr_nrm[j]     * di;
        float n1 = csr_nrm[j + 1] * di;
        float n2 = csr_nrm[j + 2] * di;
        float n3 = csr_nrm[j + 3] * di;
        float g0 = (float)g[(size_t)s0 * KC + gidx];
        float g1 = (float)g[(size_t)s1 * KC + gidx];
        float g2 = (float)g[(size_t)s2 * KC + gidx];
        float g3 = (float)g[(size_t)s3 * KC + gidx];
        a0 = fmaf(n0, g0, a0);
        a1 = fmaf(n1, g1, a1);
        a2 = fmaf(n2, g2, a2);
        a3 = fmaf(n3, g3, a3);
    }
    for (; j < end; ++j) {
        int s0 = csr_src[j];
        float n0 = csr_nrm[j] * di;
        a0 = fmaf(n0, (float)g[(size_t)s0 * KC + gidx], a0);
    }
    float acc = (a0 + a1) + (a2 + a3);
    float val = act ? (acc + b2[lane]) : -INFINITY;
    float m = val;
    #pragma unroll
    for (int o = 32; o > 0; o >>= 1) m = fmaxf(m, __shfl_xor(m, o));
    float e = act ? expf(val - m) : 0.f;
    float ssum = e;
    #pragma unroll
    for (int o = 32; o > 0; o >>= 1) ssum += __shfl_xor(ssum, o);
    {
        float sv = act ? (e / ssum) : 0.f;
        if (act) S[(size_t)wid * KC + lane] = sv;
        Sh[(size_t)wid * 64 + lane] = (f16)sv;   // padded row (zeros 50..63)
    }
}

// ---- spatial loss on padded f16 S-shadow (stride 64), wide loads ------------
__global__ __launch_bounds__(256) void loss_partial_kernel(const int* __restrict__ es,
        const int* __restrict__ ed, const float* __restrict__ pos,
        const f16* __restrict__ Sh, float* __restrict__ parts, int E) {
    float local = 0.f;
    int stride = gridDim.x * blockDim.x;
    for (int e = blockIdx.x * blockDim.x + threadIdx.x; e < E; e += stride) {
        int s = es[e], d = ed[e];
        float2 ps = ((const float2*)pos)[s];
        float2 pd = ((const float2*)pos)[d];
        float dx = ps.x - pd.x, dy = ps.y - pd.y;
        float d2 = dx * dx + dy * dy;
        const f16x8* Sa = (const f16x8*)(Sh + (size_t)s * 64);
        const f16x8* Sb = (const f16x8*)(Sh + (size_t)d * 64);
        float dot = 0.f;
        #pragma unroll
        for (int q = 0; q < 7; ++q) {            // 56 lanes cover 50 + zero pad
            f16x8 a = Sa[q], b = Sb[q];
            #pragma unroll
            for (int k = 0; k < 8; ++k)
                dot = fmaf((float)a[k], (float)b[k], dot);
        }
        local = fmaf(d2, dot, local);
    }
    __shared__ float red[256];
    red[threadIdx.x] = local;
    __syncthreads();
    for (int s = 128; s > 0; s >>= 1) {
        if ((int)threadIdx.x < s) red[threadIdx.x] += red[threadIdx.x + s];
        __syncthreads();
    }
    if (threadIdx.x == 0) parts[blockIdx.x] = red[0];
}

__global__ __launch_bounds__(1024) void loss_final_kernel(const float* __restrict__ parts,
        const float* __restrict__ sw, float* __restrict__ out, float invE) {
    __shared__ float red[1024];
    red[threadIdx.x] = parts[threadIdx.x];
    __syncthreads();
    for (int s = 512; s > 0; s >>= 1) {
        if ((int)threadIdx.x < s) red[threadIdx.x] += red[threadIdx.x + s];
        __syncthreads();
    }
    if (threadIdx.x == 0) out[0] = sw[0] * red[0] * invE;
}

// ---------------------------------------------------------------------------
extern "C" void kernel_launch(void* const* d_in, const int* in_sizes, int n_in,
                              void* d_out, int out_size, void* d_ws, size_t ws_size,
                              hipStream_t stream) {
    const float* x   = (const float*)d_in[0];
    const float* pos = (const float*)d_in[1];
    const float* W1  = (const float*)d_in[2];
    const float* b1  = (const float*)d_in[3];
    const float* W2  = (const float*)d_in[4];
    const float* b2  = (const float*)d_in[5];
    const float* sw  = (const float*)d_in[6];
    const void*  ei  = d_in[7];

    const int DH  = in_sizes[3];           // 256
    const int KC  = in_sizes[5];           // 50
    const int DIN = in_sizes[2] / DH;      // 512
    const int n   = in_sizes[0] / DIN;     // 50000
    const int E   = in_sizes[7] / 2;       // 800000

    char* p = (char*)d_ws;
    auto alloc = [&](size_t bytes) {
        char* r = p;
        p += (bytes + 255) & ~(size_t)255;
        return r;
    };
    int*   flag    = (int*)alloc(256);
    int*   es      = (int*)alloc((size_t)E * 4);
    int*   ed      = (int*)alloc((size_t)E * 4);
    int*   cnt     = (int*)alloc((size_t)n * 4);
    int*   cursor  = (int*)alloc((size_t)n * 4);
    int*   row_ptr = (int*)alloc(((size_t)n + 1) * 4);
    int*   btot    = (int*)alloc(1024 * 4);
    int*   csr     = (int*)alloc((size_t)E * 4);
    float* csr_nrm = (float*)alloc((size_t)E * 4);
    float* dinv    = (float*)alloc((size_t)n * 4);
    float* parts   = (float*)alloc(1024 * 4);
    unsigned short* Wt_hi = (unsigned short*)alloc((size_t)DIN * DH * 2);
    unsigned short* Wt_lo = (unsigned short*)alloc((size_t)DIN * DH * 2);
    f16*   W2t_hi  = (f16*)alloc((size_t)64 * DH * 2);
    f16*   W2t_lo  = (f16*)alloc((size_t)64 * DH * 2);
    f16*   h0      = (f16*)alloc((size_t)n * DH * 2);
    f16*   g       = (f16*)alloc((size_t)n * KC * 2);
    f16*   Sh      = (f16*)alloc((size_t)n * 64 * 2);

    float* S    = (float*)d_out;
    float* Lout = S + (size_t)n * KC;

    const int nb = (n + 1023) / 1024;
    const int nk = DIN / G1_BK;

    hipMemsetAsync(cnt, 0, (size_t)n * 4, stream);
    detect_i64_kernel<<<1, 256, 0, stream>>>((const unsigned*)ei, flag);
    convert_edges_kernel<<<(2 * E + 255) / 256, 256, 0, stream>>>(ei, es, ed, cnt, E, flag);
    scan_block_kernel<<<nb, 1024, 0, stream>>>(cnt, row_ptr, btot, n);
    scan_tops_kernel<<<1, 1024, 0, stream>>>(btot, nb);
    scan_finalize_kernel<<<(n + 255) / 256, 256, 0, stream>>>(row_ptr, btot, cnt, cursor, dinv, n);
    scatter_kernel<<<(E + 255) / 256, 256, 0, stream>>>(es, ed, dinv, cursor, csr, csr_nrm, E);

    // weight prep
    wsplit_kernel<<<(DIN * DH + 255) / 256, 256, 0, stream>>>(W1, Wt_hi, Wt_lo, DIN, DH, nk);
    wsplit2_kernel<<<(64 * DH + 255) / 256, 256, 0, stream>>>(W2, W2t_hi, W2t_lo, DH, KC);

    // h0 = x @ W1   (MFMA bf16x3; glds staging; fp16 output)
    dim3 g1((n + G1_BM - 1) / G1_BM, DH / G1_BN);
    gemm1_mfma<<<g1, 256, 0, stream>>>(x, Wt_hi, Wt_lo, h0, n, DIN, DH);

    // g = relu(Ahat @ h0 + b1) @ W2  (fused: h lives in LDS only; 32 nodes/blk)
    agg1_gemm2_kernel<<<(n + 31) / 32, 256, 0, stream>>>(
        h0, dinv, row_ptr, csr, csr_nrm, b1, W2t_hi, W2t_lo, g, n, DH, KC);

    // s = Ahat @ g + b2 ; S = softmax(s)  (+ padded fp16 shadow for loss)
    agg2_softmax_kernel<<<(int)(((size_t)n * 64 + 255) / 256), 256, 0, stream>>>(
        g, dinv, row_ptr, csr, csr_nrm, b2, S, Sh, n, KC);

    // L = sw * sum(d2 * <S_s, S_d>) / E
    loss_partial_kernel<<<1024, 256, 0, stream>>>(es, ed, pos, Sh, parts, E);
    loss_final_kernel<<<1, 1024, 0, stream>>>(parts, sw, Lout, 1.0f / (float)E);
}